// Round 1
// 193.557 us; speedup vs baseline: 1.0450x; 1.0450x over previous
//
#include <hip/hip_runtime.h>
#include <hip/hip_bf16.h>
#include <stdint.h>

#define BM 128
#define BN 128
#define BK 32

typedef __attribute__((ext_vector_type(8))) short bf16x8;
typedef __attribute__((ext_vector_type(4))) float f32x4;
typedef unsigned short ushort_t;

__device__ inline unsigned short f2b(float f) {
  unsigned u = __float_as_uint(f);
  unsigned r = (u + 0x7FFFu + ((u >> 16) & 1u)) >> 16;   // RNE, finite inputs
  return (unsigned short)r;
}

__device__ inline void gload_lds16(const void* g, void* l) {
  __builtin_amdgcn_global_load_lds(
      (const __attribute__((address_space(1))) void*)g,
      (__attribute__((address_space(3))) void*)l, 16, 0, 0);
}

// ---------------- f32 -> bf16 convert, 4 elems/thread ----------------
__global__ __launch_bounds__(256) void cvt_kernel(const float* __restrict__ in,
                                                  ushort_t* __restrict__ out, int n) {
  int i = (blockIdx.x * blockDim.x + threadIdx.x) * 4;
  int stride = gridDim.x * blockDim.x * 4;
  for (; i < n; i += stride) {
    float4 v = *(const float4*)(in + i);
    ushort4 o;
    o.x = f2b(v.x); o.y = f2b(v.y); o.z = f2b(v.z); o.w = f2b(v.w);
    *(ushort4*)(out + i) = o;
  }
}

// convert 3 same-size f32 arrays into one contiguous bf16 buffer
__global__ __launch_bounds__(256) void cvt3_kernel(const float* __restrict__ a,
                                                   const float* __restrict__ b,
                                                   const float* __restrict__ c,
                                                   ushort_t* __restrict__ out, int n_each) {
  const float* src = blockIdx.y == 0 ? a : (blockIdx.y == 1 ? b : c);
  ushort_t* dst = out + (size_t)blockIdx.y * n_each;
  int i = (blockIdx.x * blockDim.x + threadIdx.x) * 4;
  int stride = gridDim.x * blockDim.x * 4;
  for (; i < n_each; i += stride) {
    float4 v = *(const float4*)(src + i);
    ushort4 o;
    o.x = f2b(v.x); o.y = f2b(v.y); o.z = f2b(v.z); o.w = f2b(v.w);
    *(ushort4*)(dst + i) = o;
  }
}

__global__ __launch_bounds__(256) void concat3_f32(const float* __restrict__ a,
                                                   const float* __restrict__ b,
                                                   const float* __restrict__ c,
                                                   float* __restrict__ out, int n) {
  int i = blockIdx.x * blockDim.x + threadIdx.x;
  if (i < n) { out[i] = a[i]; out[n + i] = b[i]; out[2 * n + i] = c[i]; }
}

// ============ 256x256 8-phase GEMM (m201 template port) ============
// C[M][N] bf16 = A[M][K] @ B[N][K]^T + bias[col].  K mult of 64.
// 512 thr = 8 waves (2M x 4N); per-wave output: rows {mh*128 + wr*64 .. +63},
// cols {nh*128 + wc*32 + nf*16}.  LDS 128 KiB = [2 buf][4 slots][128x64] bf16,
// slots {0:A-rows0-127, 1:A-rows128-255, 2:B-rows0-127, 3:B-rows128-255},
// XOR swizzle byte_col ^= (row&7)<<4 (write pre-swizzled at source).
// Per K-tile: 4 phases, quadrants (mh,nh) = (0,0)(0,1)(1,1)(1,0); B(nh0) frags
// held in regs across the whole tile so each LDS slot dies in ONE phase:
//   deaths: ph1 -> A0,B0(slot read once)  ph2 -> B1   ph3 -> A1
// staging (1 half-tile = 2 gload_lds per thread, per phase):
//   ph1: A1(t+1)->nxt  ph2: A0(t+2)->cur  ph3: B0(t+2)->cur  ph4: B1(t+2)->cur
// counted vmcnt(6) ONCE per K-tile (phase 4): 3 half-tiles stay in flight.
// each stage targets a slot whose death-phase barrier has already passed.
__device__ inline void stage_half(const ushort_t* __restrict__ G, int ldg,
                                  ushort_t* slot, int w, int lane, int koff) {
  int r = w * 16 + (lane >> 3);
  int scol = ((lane & 7) ^ (lane >> 3)) << 3;  // pre-swizzled source col (elems)
  const ushort_t* src = G + (size_t)r * ldg + koff + scol;
  gload_lds16(src, slot + w * 16 * 64);
  gload_lds16(src + (size_t)8 * ldg, slot + (w * 16 + 8) * 64);
}

#define SBAR0() __builtin_amdgcn_sched_barrier(0)
#define PH_BAR() do { SBAR0(); __builtin_amdgcn_s_barrier(); SBAR0(); } while (0)
#define LGKM0() do { asm volatile("s_waitcnt lgkmcnt(0)" ::: "memory"); SBAR0(); } while (0)

#define LDA_SUB(mh)                                                              \
  _Pragma("unroll") for (int mf = 0; mf < 4; ++mf)                               \
  _Pragma("unroll") for (int ks = 0; ks < 2; ++ks) {                             \
    int r_ = (mh) * 128 + wr * 64 + mf * 16 + fr;                                \
    a[mf][ks] = *(const bf16x8*)(LA + r_ * 128 + ((ks * 64 + g16) ^ ((r_ & 7) << 4))); \
  }

#define LDB_SUB(dst, nh)                                                         \
  _Pragma("unroll") for (int nf = 0; nf < 2; ++nf)                               \
  _Pragma("unroll") for (int ks = 0; ks < 2; ++ks) {                             \
    int r_ = (nh) * 128 + wc * 32 + nf * 16 + fr;                                \
    dst[nf][ks] = *(const bf16x8*)(LB + r_ * 128 + ((ks * 64 + g16) ^ ((r_ & 7) << 4))); \
  }

#define MFMA_Q(mh, nh, bq)                                                       \
  __builtin_amdgcn_s_setprio(1);                                                 \
  _Pragma("unroll") for (int mf = 0; mf < 4; ++mf)                               \
  _Pragma("unroll") for (int nf = 0; nf < 2; ++nf)                               \
  _Pragma("unroll") for (int ks = 0; ks < 2; ++ks)                               \
    acc[(mh) * 4 + mf][(nh) * 2 + nf] = __builtin_amdgcn_mfma_f32_16x16x32_bf16( \
        a[mf][ks], bq[nf][ks], acc[(mh) * 4 + mf][(nh) * 2 + nf], 0, 0, 0);      \
  __builtin_amdgcn_s_setprio(0);

__global__ __launch_bounds__(512, 1) void gemm256_bias(
    const ushort_t* __restrict__ A, const ushort_t* __restrict__ B,
    ushort_t* __restrict__ C, const float* __restrict__ bias,
    int M, int N, int K) {
  __shared__ __align__(16) ushort_t lds[2][4][128 * 64];  // 128 KiB

  // bijective XCD swizzle (grid % 8 == 0)
  int nbx = N >> 8;
  int lin = blockIdx.x;
  int cpx = gridDim.x >> 3;
  int sw = (lin & 7) * cpx + (lin >> 3);
  int by = sw / nbx, bx = sw - by * nbx;

  int tid = threadIdx.x, lane = tid & 63, w = tid >> 6;
  int wr = w >> 2, wc = w & 3;                  // 2x4 wave grid
  int fr = lane & 15, g16 = (lane >> 4) * 16;   // frag row / byte col group

  const ushort_t* Ab = A + (size_t)by * 256 * K;
  const ushort_t* Bb = B + (size_t)bx * 256 * K;
  const ushort_t* A0g = Ab;
  const ushort_t* A1g = Ab + (size_t)128 * K;
  const ushort_t* B0g = Bb;
  const ushort_t* B1g = Bb + (size_t)128 * K;

  f32x4 acc[8][4];
#pragma unroll
  for (int i = 0; i < 8; i++)
#pragma unroll
    for (int j = 0; j < 4; j++) acc[i][j] = (f32x4)(0.f);

  int nt = K >> 6;

  // ---- prologue: tile0 fully + first 3 half-tiles of tile1 ----
  stage_half(A0g, K, &lds[0][0][0], w, lane, 0);
  stage_half(A1g, K, &lds[0][1][0], w, lane, 0);
  stage_half(B0g, K, &lds[0][2][0], w, lane, 0);
  stage_half(B1g, K, &lds[0][3][0], w, lane, 0);
  if (nt > 1) {
    stage_half(A0g, K, &lds[1][0][0], w, lane, 64);
    stage_half(B0g, K, &lds[1][2][0], w, lane, 64);
    stage_half(B1g, K, &lds[1][3][0], w, lane, 64);
    asm volatile("s_waitcnt vmcnt(6)" ::: "memory");  // tile0's 8 loads landed
  } else {
    asm volatile("s_waitcnt vmcnt(0)" ::: "memory");
  }
  PH_BAR();

  for (int t = 0; t < nt; ++t) {
    const int cur = t & 1, nxt = cur ^ 1;
    const char* LA = (const char*)&lds[cur][0][0];
    const char* LB = (const char*)&lds[cur][2][0];
    bf16x8 a[4][2], b0[2][2], b1[2][2];

    // -- phase 1: quadrant (0,0); 12 ds_reads; stage A1(t+1) --
    LDA_SUB(0);
    LDB_SUB(b0, 0);
    if (t + 1 < nt) stage_half(A1g, K, &lds[nxt][1][0], w, lane, (t + 1) * 64);
    asm volatile("s_waitcnt lgkmcnt(8)" ::: "memory");
    PH_BAR();
    LGKM0();
    MFMA_Q(0, 0, b0);
    PH_BAR();

    // -- phase 2: quadrant (0,1); 4 ds_reads; stage A0(t+2) (slot died ph1) --
    LDB_SUB(b1, 1);
    if (t + 2 < nt) stage_half(A0g, K, &lds[cur][0][0], w, lane, (t + 2) * 64);
    PH_BAR();
    LGKM0();
    MFMA_Q(0, 1, b1);
    PH_BAR();

    // -- phase 3: quadrant (1,1); 8 ds_reads; stage B0(t+2) (slot died ph1) --
    LDA_SUB(1);
    if (t + 2 < nt) stage_half(B0g, K, &lds[cur][2][0], w, lane, (t + 2) * 64);
    PH_BAR();
    LGKM0();
    MFMA_Q(1, 1, b1);
    PH_BAR();

    // -- phase 4: quadrant (1,0); 0 ds_reads; stage B1(t+2) (slot died ph2) --
    if (t + 2 < nt) {
      stage_half(B1g, K, &lds[cur][3][0], w, lane, (t + 2) * 64);
      asm volatile("s_waitcnt vmcnt(6)" ::: "memory");  // tile t+1 landed; 3 halves in flight
    } else if (t + 1 < nt) {
      asm volatile("s_waitcnt vmcnt(0)" ::: "memory");  // drain: tile t+1 is the last
    }
    PH_BAR();
    MFMA_Q(1, 0, b0);
    PH_BAR();
  }

  // epilogue: C/D layout col=lane&15, row=(lane>>4)*4+j
  int c2 = lane & 15;
  int rb = (lane >> 4) * 4;
#pragma unroll
  for (int ni = 0; ni < 4; ++ni) {
    int nh = ni >> 1, nf = ni & 1;
    int col = bx * 256 + nh * 128 + wc * 32 + nf * 16 + c2;
    float bv = bias[col];
#pragma unroll
    for (int mi = 0; mi < 8; ++mi) {
      int mh = mi >> 2, mf = mi & 3;
#pragma unroll
      for (int j = 0; j < 4; ++j) {
        int row = by * 256 + mh * 128 + wr * 64 + mf * 16 + rb + j;
        C[(size_t)row * N + col] = f2b(acc[mi][ni][j] + bv);
      }
    }
  }
}

#undef LDA_SUB
#undef LDB_SUB
#undef MFMA_Q
#undef PH_BAR
#undef LGKM0
#undef SBAR0

// ---------------- 128x128 GEMM  C = A @ B^T  (A:[M][K], B:[N][K], bf16) ----------------
// MODE 1: P bf16 = exp(acc*scale) masked causal; accumulate rowsum atomically (scores)
// MODE 2: C f32  = acc / rowsum[row], K capped at (by+1)*BM (PV, causal-zero P tail)
template <int MODE>
__global__ __launch_bounds__(256, 2) void gemm_bt(
    const ushort_t* __restrict__ A, const ushort_t* __restrict__ B,
    void* __restrict__ Cv, float* __restrict__ rowsum,
    int M, int N, int K, int lda, int ldb, int ldc,
    long bsA, long bsB, long bsC, float scale) {
  int bx = blockIdx.x, by = blockIdx.y, bz = blockIdx.z;
  if (MODE == 1 && bx > by) return;  // fully-masked causal block: never read

  const ushort_t* Ab = A + (size_t)bz * bsA + (size_t)by * BM * lda;
  const ushort_t* Bb = B + (size_t)bz * bsB + (size_t)bx * BN * ldb;

  int Keff = K;
  if (MODE == 2) { int cap = (by + 1) * BM; Keff = cap < K ? cap : K; }

  __shared__ __align__(16) ushort_t As[BM * BK];
  __shared__ __align__(16) ushort_t Bs[BN * BK];

  int tid = threadIdx.x;
  int lane = tid & 63;
  int w = tid >> 6;
  int wm = w >> 1, wn = w & 1;

  f32x4 acc[4][4];
#pragma unroll
  for (int i = 0; i < 4; i++)
#pragma unroll
    for (int j = 0; j < 4; j++) acc[i][j] = (f32x4)(0.f);

  int lrow = lane >> 2;
  int lcol = (lane & 3) * 8;

  int nk = Keff / BK;
  for (int kt = 0; kt < nk; ++kt) {
    const ushort_t* Abase = Ab + kt * BK + lcol + (size_t)lrow * lda;
    const ushort_t* Bbase = Bb + kt * BK + lcol + (size_t)lrow * ldb;
#pragma unroll
    for (int j = 0; j < 2; ++j) {
      int ch = w * 2 + j;
      gload_lds16(Abase + (size_t)ch * 16 * lda, &As[ch * 16 * BK]);
      gload_lds16(Bbase + (size_t)ch * 16 * ldb, &Bs[ch * 16 * BK]);
    }
    __syncthreads();

    int fr = lane & 15, koff = (lane >> 4) * 8;
    bf16x8 af[4], bf[4];
#pragma unroll
    for (int i = 0; i < 4; i++)
      af[i] = *(const bf16x8*)&As[(wm * 64 + i * 16 + fr) * BK + koff];
#pragma unroll
    for (int i = 0; i < 4; i++)
      bf[i] = *(const bf16x8*)&Bs[(wn * 64 + i * 16 + fr) * BK + koff];
#pragma unroll
    for (int mi = 0; mi < 4; mi++)
#pragma unroll
      for (int ni = 0; ni < 4; ni++)
        acc[mi][ni] = __builtin_amdgcn_mfma_f32_16x16x32_bf16(af[mi], bf[ni], acc[mi][ni], 0, 0, 0);
    __syncthreads();
  }

  int c = lane & 15;
  int rb = (lane >> 4) * 4;
  if (MODE == 1) {
    ushort_t* Cp = (ushort_t*)Cv + (size_t)bz * bsC;
#pragma unroll
    for (int mi = 0; mi < 4; mi++)
#pragma unroll
      for (int j = 0; j < 4; j++) {
        int row = by * BM + wm * 64 + mi * 16 + rb + j;
        float rsum = 0.f;
#pragma unroll
        for (int ni = 0; ni < 4; ni++) {
          int col = bx * BN + wn * 64 + ni * 16 + c;
          float e = 0.f;
          if (bx != by || col <= row) e = __expf(acc[mi][ni][j] * scale);
          rsum += e;
          Cp[(size_t)row * ldc + col] = f2b(e);
        }
#pragma unroll
        for (int o = 1; o < 16; o <<= 1) rsum += __shfl_xor(rsum, o);
        if (c == 0) atomicAdd(&rowsum[(size_t)bz * M + row], rsum);
      }
  } else {
    float* C = (float*)Cv + (size_t)bz * bsC;
#pragma unroll
    for (int mi = 0; mi < 4; mi++)
#pragma unroll
      for (int j = 0; j < 4; j++) {
        int row = by * BM + wm * 64 + mi * 16 + rb + j;
        float inv = 1.0f / rowsum[(size_t)bz * M + row];
#pragma unroll
        for (int ni = 0; ni < 4; ni++) {
          int col = bx * BN + wn * 64 + ni * 16 + c;
          C[(size_t)row * ldc + col] = acc[mi][ni][j] * inv;
        }
      }
  }
}

// ---------------- bf16 transpose [rows][cols] -> [cols][rows], strided input ----------------
__global__ __launch_bounds__(256) void transpose2d(const ushort_t* __restrict__ in,
                                                   ushort_t* __restrict__ out,
                                                   int rows, int cols, int ld_in,
                                                   long bs_in, long bs_out) {
  __shared__ ushort_t tile[32][33];
  int b = blockIdx.z;
  in += (size_t)b * bs_in;
  out += (size_t)b * bs_out;
  int c0 = blockIdx.x * 32, r0 = blockIdx.y * 32;
  int tx = threadIdx.x & 31, ty = threadIdx.x >> 5;
#pragma unroll
  for (int i = ty; i < 32; i += 8) tile[i][tx] = in[(size_t)(r0 + i) * ld_in + c0 + tx];
  __syncthreads();
#pragma unroll
  for (int i = ty; i < 32; i += 8) out[(size_t)(c0 + i) * rows + r0 + tx] = tile[tx][i];
}

extern "C" void kernel_launch(void* const* d_in, const int* in_sizes, int n_in,
                              void* d_out, int out_size, void* d_ws, size_t ws_size,
                              hipStream_t stream) {
  const int Bb = 4, S = 2048, E = 1024, A = 1024;
  const int N3 = 3 * A;             // fused projection width 3072
  const size_t M = (size_t)Bb * S;  // 8192
  const float* emb = (const float*)d_in[0];
  const float* Wq = (const float*)d_in[1];
  const float* bq = (const float*)d_in[2];
  const float* Wk = (const float*)d_in[3];
  const float* bk = (const float*)d_in[4];
  const float* Wv = (const float*)d_in[5];
  const float* bv = (const float*)d_in[6];
  float* out = (float*)d_out;

  char* ws = (char*)d_ws;
  // layout (byte offsets):
  ushort_t* QKV  = (ushort_t*)(ws + 0);           // 48 MiB [8192][3072]: Q|K|V
  ushort_t* Vt   = (ushort_t*)(ws + 50331648);    // 16 MiB [b][A][S]
  ushort_t* P    = (ushort_t*)(ws + 67108864);    // 32 MiB [b][S][S] bf16 (unnormalized exp)
  float* rowsum  = (float*)(ws + 100663296);      // 32 KiB [b*S]
  ushort_t* embB = (ushort_t*)(ws + 100696064);   // 16 MiB
  ushort_t* WB   = (ushort_t*)(ws + 117473280);   // 6 MiB = Wq|Wk|Wv bf16 [3072][1024]
  float*    bqkv = (float*)(ws + 123764736);      // 12 KiB
  if (ws_size < 157286400ull) return;             // refuse to corrupt

  cvt_kernel<<<2048, 256, 0, stream>>>(emb, embB, (int)(M * E));
  cvt3_kernel<<<dim3(256, 3), 256, 0, stream>>>(Wq, Wk, Wv, WB, A * E);
  concat3_f32<<<4, 256, 0, stream>>>(bq, bk, bv, bqkv, A);
  hipMemsetAsync(rowsum, 0, (size_t)M * sizeof(float), stream);

  // fused QKV projection: M=8192, N=3072, K=1024 -> 384 blocks of 512 thr
  gemm256_bias<<<dim3((M / 256) * (N3 / 256)), dim3(512), 0, stream>>>(
      embB, WB, QKV, bqkv, (int)M, N3, E);

  // V (cols 2048..3071 of QKV, ld 3072) -> Vt [A][S] per batch
  transpose2d<<<dim3(A / 32, S / 32, Bb), dim3(256), 0, stream>>>(
      QKV + 2 * A, Vt, S, A, N3, (long)S * N3, (long)A * S);

  // scores -> P = exp(QK^T/sqrt(dk)) bf16 + rowsum atomics
  gemm_bt<1><<<dim3(S / BN, S / BM, Bb), dim3(256), 0, stream>>>(
      QKV /*Q*/, QKV + A /*K*/, P, rowsum, S, S, A, N3, N3, S,
      (long)S * N3, (long)S * N3, (long)S * S, 0.03125f);

  // PV: per batch M=2048, N=1024, K=2048 (capped per block-row), divide by rowsum
  gemm_bt<2><<<dim3(A / BN, S / BM, Bb), dim3(256), 0, stream>>>(
      P, Vt, out, rowsum, S, A, S, S, S, A,
      (long)S * S, (long)A * S, (long)S * A, 1.f);
}

// Round 2
// 171.081 us; speedup vs baseline: 1.1823x; 1.1314x over previous
//
#include <hip/hip_runtime.h>
#include <hip/hip_bf16.h>
#include <stdint.h>

#define BM 128
#define BN 128
#define BK 64

typedef __attribute__((ext_vector_type(8))) short bf16x8;
typedef __attribute__((ext_vector_type(4))) float f32x4;
typedef unsigned short ushort_t;

__device__ inline unsigned short f2b(float f) {
  unsigned u = __float_as_uint(f);
  unsigned r = (u + 0x7FFFu + ((u >> 16) & 1u)) >> 16;   // RNE, finite inputs
  return (unsigned short)r;
}

__device__ inline void gload_lds16(const void* g, void* l) {
  __builtin_amdgcn_global_load_lds(
      (const __attribute__((address_space(1))) void*)g,
      (__attribute__((address_space(3))) void*)l, 16, 0, 0);
}

// ---------------- f32 -> bf16 convert, 4 elems/thread ----------------
__global__ __launch_bounds__(256) void cvt_kernel(const float* __restrict__ in,
                                                  ushort_t* __restrict__ out, int n) {
  int i = (blockIdx.x * blockDim.x + threadIdx.x) * 4;
  int stride = gridDim.x * blockDim.x * 4;
  for (; i < n; i += stride) {
    float4 v = *(const float4*)(in + i);
    ushort4 o;
    o.x = f2b(v.x); o.y = f2b(v.y); o.z = f2b(v.z); o.w = f2b(v.w);
    *(ushort4*)(out + i) = o;
  }
}

// convert 3 same-size f32 arrays into one contiguous bf16 buffer
__global__ __launch_bounds__(256) void cvt3_kernel(const float* __restrict__ a,
                                                   const float* __restrict__ b,
                                                   const float* __restrict__ c,
                                                   ushort_t* __restrict__ out, int n_each) {
  const float* src = blockIdx.y == 0 ? a : (blockIdx.y == 1 ? b : c);
  ushort_t* dst = out + (size_t)blockIdx.y * n_each;
  int i = (blockIdx.x * blockDim.x + threadIdx.x) * 4;
  int stride = gridDim.x * blockDim.x * 4;
  for (; i < n_each; i += stride) {
    float4 v = *(const float4*)(src + i);
    ushort4 o;
    o.x = f2b(v.x); o.y = f2b(v.y); o.z = f2b(v.z); o.w = f2b(v.w);
    *(ushort4*)(dst + i) = o;
  }
}

__global__ __launch_bounds__(256) void concat3_f32(const float* __restrict__ a,
                                                   const float* __restrict__ b,
                                                   const float* __restrict__ c,
                                                   float* __restrict__ out, int n) {
  int i = blockIdx.x * blockDim.x + threadIdx.x;
  if (i < n) { out[i] = a[i]; out[n + i] = b[i]; out[2 * n + i] = c[i]; }
}

// ============ 256x256 8-phase GEMM (m201 template port) ============
// C[M][N] bf16 = A[M][K] @ B[N][K]^T + bias[col].  K mult of 64.
// 512 thr = 8 waves (2M x 4N); per-wave output: rows {mh*128 + wr*64 .. +63},
// cols {nh*128 + wc*32 + nf*16}.  LDS 128 KiB = [2 buf][4 slots][128x64] bf16,
// slots {0:A-rows0-127, 1:A-rows128-255, 2:B-rows0-127, 3:B-rows128-255},
// XOR swizzle byte_col ^= (row&7)<<4 (write pre-swizzled at source).
// Per K-tile: 4 phases, quadrants (mh,nh) = (0,0)(0,1)(1,1)(1,0); B(nh0) frags
// held in regs across the whole tile so each LDS slot dies in ONE phase:
//   deaths: ph1 -> A0,B0(slot read once)  ph2 -> B1   ph3 -> A1
// staging (1 half-tile = 2 gload_lds per thread, per phase):
//   ph1: A1(t+1)->nxt  ph2: A0(t+2)->cur  ph3: B0(t+2)->cur  ph4: B1(t+2)->cur
// counted vmcnt(6) ONCE per K-tile (phase 4): 3 half-tiles stay in flight.
// each stage targets a slot whose death-phase barrier has already passed.
__device__ inline void stage_half(const ushort_t* __restrict__ G, int ldg,
                                  ushort_t* slot, int w, int lane, int koff) {
  int r = w * 16 + (lane >> 3);
  int scol = ((lane & 7) ^ (lane >> 3)) << 3;  // pre-swizzled source col (elems)
  const ushort_t* src = G + (size_t)r * ldg + koff + scol;
  gload_lds16(src, slot + w * 16 * 64);
  gload_lds16(src + (size_t)8 * ldg, slot + (w * 16 + 8) * 64);
}

#define SBAR0() __builtin_amdgcn_sched_barrier(0)
#define PH_BAR() do { SBAR0(); __builtin_amdgcn_s_barrier(); SBAR0(); } while (0)
#define LGKM0() do { asm volatile("s_waitcnt lgkmcnt(0)" ::: "memory"); SBAR0(); } while (0)

#define LDA_SUB(mh)                                                              \
  _Pragma("unroll") for (int mf = 0; mf < 4; ++mf)                               \
  _Pragma("unroll") for (int ks = 0; ks < 2; ++ks) {                             \
    int r_ = (mh) * 128 + wr * 64 + mf * 16 + fr;                                \
    a[mf][ks] = *(const bf16x8*)(LA + r_ * 128 + ((ks * 64 + g16) ^ ((r_ & 7) << 4))); \
  }

#define LDB_SUB(dst, nh)                                                         \
  _Pragma("unroll") for (int nf = 0; nf < 2; ++nf)                               \
  _Pragma("unroll") for (int ks = 0; ks < 2; ++ks) {                             \
    int r_ = (nh) * 128 + wc * 32 + nf * 16 + fr;                                \
    dst[nf][ks] = *(const bf16x8*)(LB + r_ * 128 + ((ks * 64 + g16) ^ ((r_ & 7) << 4))); \
  }

#define MFMA_Q(mh, nh, bq)                                                       \
  __builtin_amdgcn_s_setprio(1);                                                 \
  _Pragma("unroll") for (int mf = 0; mf < 4; ++mf)                               \
  _Pragma("unroll") for (int nf = 0; nf < 2; ++nf)                               \
  _Pragma("unroll") for (int ks = 0; ks < 2; ++ks)                               \
    acc[(mh) * 4 + mf][(nh) * 2 + nf] = __builtin_amdgcn_mfma_f32_16x16x32_bf16( \
        a[mf][ks], bq[nf][ks], acc[(mh) * 4 + mf][(nh) * 2 + nf], 0, 0, 0);      \
  __builtin_amdgcn_s_setprio(0);

__global__ __launch_bounds__(512, 1) void gemm256_bias(
    const ushort_t* __restrict__ A, const ushort_t* __restrict__ B,
    ushort_t* __restrict__ C, const float* __restrict__ bias,
    int M, int N, int K) {
  __shared__ __align__(16) ushort_t lds[2][4][128 * 64];  // 128 KiB

  // bijective XCD swizzle (grid % 8 == 0)
  int nbx = N >> 8;
  int lin = blockIdx.x;
  int cpx = gridDim.x >> 3;
  int sw = (lin & 7) * cpx + (lin >> 3);
  int by = sw / nbx, bx = sw - by * nbx;

  int tid = threadIdx.x, lane = tid & 63, w = tid >> 6;
  int wr = w >> 2, wc = w & 3;                  // 2x4 wave grid
  int fr = lane & 15, g16 = (lane >> 4) * 16;   // frag row / byte col group

  const ushort_t* Ab = A + (size_t)by * 256 * K;
  const ushort_t* Bb = B + (size_t)bx * 256 * K;
  const ushort_t* A0g = Ab;
  const ushort_t* A1g = Ab + (size_t)128 * K;
  const ushort_t* B0g = Bb;
  const ushort_t* B1g = Bb + (size_t)128 * K;

  f32x4 acc[8][4];
#pragma unroll
  for (int i = 0; i < 8; i++)
#pragma unroll
    for (int j = 0; j < 4; j++) acc[i][j] = (f32x4)(0.f);

  int nt = K >> 6;

  // ---- prologue: tile0 fully + first 3 half-tiles of tile1 ----
  stage_half(A0g, K, &lds[0][0][0], w, lane, 0);
  stage_half(A1g, K, &lds[0][1][0], w, lane, 0);
  stage_half(B0g, K, &lds[0][2][0], w, lane, 0);
  stage_half(B1g, K, &lds[0][3][0], w, lane, 0);
  if (nt > 1) {
    stage_half(A0g, K, &lds[1][0][0], w, lane, 64);
    stage_half(B0g, K, &lds[1][2][0], w, lane, 64);
    stage_half(B1g, K, &lds[1][3][0], w, lane, 64);
    asm volatile("s_waitcnt vmcnt(6)" ::: "memory");  // tile0's 8 loads landed
  } else {
    asm volatile("s_waitcnt vmcnt(0)" ::: "memory");
  }
  PH_BAR();

  for (int t = 0; t < nt; ++t) {
    const int cur = t & 1, nxt = cur ^ 1;
    const char* LA = (const char*)&lds[cur][0][0];
    const char* LB = (const char*)&lds[cur][2][0];
    bf16x8 a[4][2], b0[2][2], b1[2][2];

    // -- phase 1: quadrant (0,0); 12 ds_reads; stage A1(t+1) --
    LDA_SUB(0);
    LDB_SUB(b0, 0);
    if (t + 1 < nt) stage_half(A1g, K, &lds[nxt][1][0], w, lane, (t + 1) * 64);
    asm volatile("s_waitcnt lgkmcnt(8)" ::: "memory");
    PH_BAR();
    LGKM0();
    MFMA_Q(0, 0, b0);
    PH_BAR();

    // -- phase 2: quadrant (0,1); 4 ds_reads; stage A0(t+2) (slot died ph1) --
    LDB_SUB(b1, 1);
    if (t + 2 < nt) stage_half(A0g, K, &lds[cur][0][0], w, lane, (t + 2) * 64);
    PH_BAR();
    LGKM0();
    MFMA_Q(0, 1, b1);
    PH_BAR();

    // -- phase 3: quadrant (1,1); 8 ds_reads; stage B0(t+2) (slot died ph1) --
    LDA_SUB(1);
    if (t + 2 < nt) stage_half(B0g, K, &lds[cur][2][0], w, lane, (t + 2) * 64);
    PH_BAR();
    LGKM0();
    MFMA_Q(1, 1, b1);
    PH_BAR();

    // -- phase 4: quadrant (1,0); 0 ds_reads; stage B1(t+2) (slot died ph2) --
    if (t + 2 < nt) {
      stage_half(B1g, K, &lds[cur][3][0], w, lane, (t + 2) * 64);
      asm volatile("s_waitcnt vmcnt(6)" ::: "memory");  // tile t+1 landed; 3 halves in flight
    } else if (t + 1 < nt) {
      asm volatile("s_waitcnt vmcnt(0)" ::: "memory");  // drain: tile t+1 is the last
    }
    PH_BAR();
    MFMA_Q(1, 0, b0);
    PH_BAR();
  }

  // epilogue: C/D layout col=lane&15, row=(lane>>4)*4+j
  int c2 = lane & 15;
  int rb = (lane >> 4) * 4;
#pragma unroll
  for (int ni = 0; ni < 4; ++ni) {
    int nh = ni >> 1, nf = ni & 1;
    int col = bx * 256 + nh * 128 + wc * 32 + nf * 16 + c2;
    float bv = bias[col];
#pragma unroll
    for (int mi = 0; mi < 8; ++mi) {
      int mh = mi >> 2, mf = mi & 3;
#pragma unroll
      for (int j = 0; j < 4; ++j) {
        int row = by * 256 + mh * 128 + wr * 64 + mf * 16 + rb + j;
        C[(size_t)row * N + col] = f2b(acc[mi][ni][j] + bv);
      }
    }
  }
}

#undef LDA_SUB
#undef LDB_SUB
#undef MFMA_Q
#undef PH_BAR
#undef LGKM0
#undef SBAR0

// ---------------- 128x128 GEMM  C = A @ B^T  (A:[M][K], B:[N][K], bf16) ----------------
// BK=64, XOR-swizzled LDS (byte_col ^= (row&7)<<4, same pre-swizzled-source /
// swizzled-read pair as gemm256_bias) -> conflict-free ds_read_b128.
// 32 MFMA per barrier; 3 blocks/CU.
// MODE 1: P bf16 = exp(acc*scale) masked causal; accumulate rowsum atomically (scores)
// MODE 2: C f32  = acc / rowsum[row], K capped at (by+1)*BM (PV, causal-zero P tail)
template <int MODE>
__global__ __launch_bounds__(256, 3) void gemm_bt(
    const ushort_t* __restrict__ A, const ushort_t* __restrict__ B,
    void* __restrict__ Cv, float* __restrict__ rowsum,
    int M, int N, int K, int lda, int ldb, int ldc,
    long bsA, long bsB, long bsC, float scale) {
  int bx = blockIdx.x, by = blockIdx.y, bz = blockIdx.z;
  if (MODE == 1 && bx > by) return;  // fully-masked causal block: never read

  const ushort_t* Ab = A + (size_t)bz * bsA + (size_t)by * BM * lda;
  const ushort_t* Bb = B + (size_t)bz * bsB + (size_t)bx * BN * ldb;

  int Keff = K;
  if (MODE == 2) { int cap = (by + 1) * BM; Keff = cap < K ? cap : K; }

  __shared__ __align__(16) ushort_t As[BM * BK];  // 16 KiB
  __shared__ __align__(16) ushort_t Bs[BN * BK];  // 16 KiB

  int tid = threadIdx.x;
  int lane = tid & 63;
  int w = tid >> 6;                 // 4 waves
  int wm = w >> 1, wn = w & 1;

  f32x4 acc[4][4];
#pragma unroll
  for (int i = 0; i < 4; i++)
#pragma unroll
    for (int j = 0; j < 4; j++) acc[i][j] = (f32x4)(0.f);

  // staging: wave w covers rows w*32 .. w*32+31 (4 gload_lds of 8 rows each)
  int srow = lane >> 3;                      // 0..7 within 8-row group
  int scol = ((lane & 7) ^ srow) << 3;       // pre-swizzled source col (elems)
  int fr = lane & 15, g16 = (lane >> 4) * 16;

  int nk = Keff / BK;
  for (int kt = 0; kt < nk; ++kt) {
    const ushort_t* Abase = Ab + (size_t)(w * 32 + srow) * lda + kt * BK + scol;
    const ushort_t* Bbase = Bb + (size_t)(w * 32 + srow) * ldb + kt * BK + scol;
#pragma unroll
    for (int j = 0; j < 4; ++j) {
      gload_lds16(Abase + (size_t)(j * 8) * lda, &As[(w * 32 + j * 8) * BK]);
      gload_lds16(Bbase + (size_t)(j * 8) * ldb, &Bs[(w * 32 + j * 8) * BK]);
    }
    __syncthreads();

    bf16x8 af[4][2], bf[4][2];
#pragma unroll
    for (int i = 0; i < 4; i++)
#pragma unroll
      for (int ks = 0; ks < 2; ++ks) {
        int ra = wm * 64 + i * 16 + fr;
        af[i][ks] = *(const bf16x8*)((const char*)As + ra * 128 +
                                     ((ks * 64 + g16) ^ ((ra & 7) << 4)));
        int rb2 = wn * 64 + i * 16 + fr;
        bf[i][ks] = *(const bf16x8*)((const char*)Bs + rb2 * 128 +
                                     ((ks * 64 + g16) ^ ((rb2 & 7) << 4)));
      }
#pragma unroll
    for (int mi = 0; mi < 4; mi++)
#pragma unroll
      for (int ni = 0; ni < 4; ni++)
#pragma unroll
        for (int ks = 0; ks < 2; ++ks)
          acc[mi][ni] = __builtin_amdgcn_mfma_f32_16x16x32_bf16(
              af[mi][ks], bf[ni][ks], acc[mi][ni], 0, 0, 0);
    __syncthreads();
  }

  int c = lane & 15;
  int rb = (lane >> 4) * 4;
  if (MODE == 1) {
    ushort_t* Cp = (ushort_t*)Cv + (size_t)bz * bsC;
#pragma unroll
    for (int mi = 0; mi < 4; mi++)
#pragma unroll
      for (int j = 0; j < 4; j++) {
        int row = by * BM + wm * 64 + mi * 16 + rb + j;
        float rsum = 0.f;
#pragma unroll
        for (int ni = 0; ni < 4; ni++) {
          int col = bx * BN + wn * 64 + ni * 16 + c;
          float e = 0.f;
          if (bx != by || col <= row) e = __expf(acc[mi][ni][j] * scale);
          rsum += e;
          Cp[(size_t)row * ldc + col] = f2b(e);
        }
#pragma unroll
        for (int o = 1; o < 16; o <<= 1) rsum += __shfl_xor(rsum, o);
        if (c == 0) atomicAdd(&rowsum[(size_t)bz * M + row], rsum);
      }
  } else {
    float* C = (float*)Cv + (size_t)bz * bsC;
#pragma unroll
    for (int mi = 0; mi < 4; mi++)
#pragma unroll
      for (int j = 0; j < 4; j++) {
        int row = by * BM + wm * 64 + mi * 16 + rb + j;
        float inv = 1.0f / rowsum[(size_t)bz * M + row];
#pragma unroll
        for (int ni = 0; ni < 4; ni++) {
          int col = bx * BN + wn * 64 + ni * 16 + c;
          C[(size_t)row * ldc + col] = acc[mi][ni][j] * inv;
        }
      }
  }
}

// ---------------- bf16 transpose [rows][cols] -> [cols][rows], strided input ----------------
__global__ __launch_bounds__(256) void transpose2d(const ushort_t* __restrict__ in,
                                                   ushort_t* __restrict__ out,
                                                   int rows, int cols, int ld_in,
                                                   long bs_in, long bs_out) {
  __shared__ ushort_t tile[32][33];
  int b = blockIdx.z;
  in += (size_t)b * bs_in;
  out += (size_t)b * bs_out;
  int c0 = blockIdx.x * 32, r0 = blockIdx.y * 32;
  int tx = threadIdx.x & 31, ty = threadIdx.x >> 5;
#pragma unroll
  for (int i = ty; i < 32; i += 8) tile[i][tx] = in[(size_t)(r0 + i) * ld_in + c0 + tx];
  __syncthreads();
#pragma unroll
  for (int i = ty; i < 32; i += 8) out[(size_t)(c0 + i) * rows + r0 + tx] = tile[tx][i];
}

extern "C" void kernel_launch(void* const* d_in, const int* in_sizes, int n_in,
                              void* d_out, int out_size, void* d_ws, size_t ws_size,
                              hipStream_t stream) {
  const int Bb = 4, S = 2048, E = 1024, A = 1024;
  const int N3 = 3 * A;             // fused projection width 3072
  const size_t M = (size_t)Bb * S;  // 8192
  const float* emb = (const float*)d_in[0];
  const float* Wq = (const float*)d_in[1];
  const float* bq = (const float*)d_in[2];
  const float* Wk = (const float*)d_in[3];
  const float* bk = (const float*)d_in[4];
  const float* Wv = (const float*)d_in[5];
  const float* bv = (const float*)d_in[6];
  float* out = (float*)d_out;

  char* ws = (char*)d_ws;
  // layout (byte offsets):
  ushort_t* QKV  = (ushort_t*)(ws + 0);           // 48 MiB [8192][3072]: Q|K|V
  ushort_t* Vt   = (ushort_t*)(ws + 50331648);    // 16 MiB [b][A][S]
  ushort_t* P    = (ushort_t*)(ws + 67108864);    // 32 MiB [b][S][S] bf16 (unnormalized exp)
  float* rowsum  = (float*)(ws + 100663296);      // 32 KiB [b*S]
  ushort_t* embB = (ushort_t*)(ws + 100696064);   // 16 MiB
  ushort_t* WB   = (ushort_t*)(ws + 117473280);   // 6 MiB = Wq|Wk|Wv bf16 [3072][1024]
  float*    bqkv = (float*)(ws + 123764736);      // 12 KiB
  if (ws_size < 157286400ull) return;             // refuse to corrupt

  cvt_kernel<<<2048, 256, 0, stream>>>(emb, embB, (int)(M * E));
  cvt3_kernel<<<dim3(256, 3), 256, 0, stream>>>(Wq, Wk, Wv, WB, A * E);
  concat3_f32<<<4, 256, 0, stream>>>(bq, bk, bv, bqkv, A);
  hipMemsetAsync(rowsum, 0, (size_t)M * sizeof(float), stream);

  // fused QKV projection: M=8192, N=3072, K=1024 -> 384 blocks of 512 thr
  gemm256_bias<<<dim3((M / 256) * (N3 / 256)), dim3(512), 0, stream>>>(
      embB, WB, QKV, bqkv, (int)M, N3, E);

  // V (cols 2048..3071 of QKV, ld 3072) -> Vt [A][S] per batch
  transpose2d<<<dim3(A / 32, S / 32, Bb), dim3(256), 0, stream>>>(
      QKV + 2 * A, Vt, S, A, N3, (long)S * N3, (long)A * S);

  // scores -> P = exp(QK^T/sqrt(dk)) bf16 + rowsum atomics
  gemm_bt<1><<<dim3(S / BN, S / BM, Bb), dim3(256), 0, stream>>>(
      QKV /*Q*/, QKV + A /*K*/, P, rowsum, S, S, A, N3, N3, S,
      (long)S * N3, (long)S * N3, (long)S * S, 0.03125f);

  // PV: per batch M=2048, N=1024, K=2048 (capped per block-row), divide by rowsum
  gemm_bt<2><<<dim3(A / BN, S / BM, Bb), dim3(256), 0, stream>>>(
      P, Vt, out, rowsum, S, A, S, S, S, A,
      (long)S * S, (long)A * S, (long)S * A, 1.f);
}

// Round 3
// 167.213 us; speedup vs baseline: 1.2096x; 1.0231x over previous
//
#include <hip/hip_runtime.h>
#include <hip/hip_bf16.h>
#include <stdint.h>

#define BM 128
#define BN 128
#define BK 64

typedef __attribute__((ext_vector_type(8))) short bf16x8;
typedef __attribute__((ext_vector_type(4))) float f32x4;
typedef unsigned short ushort_t;

__device__ inline unsigned short f2b(float f) {
  unsigned u = __float_as_uint(f);
  unsigned r = (u + 0x7FFFu + ((u >> 16) & 1u)) >> 16;   // RNE, finite inputs
  return (unsigned short)r;
}

__device__ inline void gload_lds16(const void* g, void* l) {
  __builtin_amdgcn_global_load_lds(
      (const __attribute__((address_space(1))) void*)g,
      (__attribute__((address_space(3))) void*)l, 16, 0, 0);
}

// ---------------- f32 -> bf16 convert, 4 elems/thread ----------------
__global__ __launch_bounds__(256) void cvt_kernel(const float* __restrict__ in,
                                                  ushort_t* __restrict__ out, int n) {
  int i = (blockIdx.x * blockDim.x + threadIdx.x) * 4;
  int stride = gridDim.x * blockDim.x * 4;
  for (; i < n; i += stride) {
    float4 v = *(const float4*)(in + i);
    ushort4 o;
    o.x = f2b(v.x); o.y = f2b(v.y); o.z = f2b(v.z); o.w = f2b(v.w);
    *(ushort4*)(out + i) = o;
  }
}

// convert 3 same-size f32 arrays into one contiguous bf16 buffer
__global__ __launch_bounds__(256) void cvt3_kernel(const float* __restrict__ a,
                                                   const float* __restrict__ b,
                                                   const float* __restrict__ c,
                                                   ushort_t* __restrict__ out, int n_each) {
  const float* src = blockIdx.y == 0 ? a : (blockIdx.y == 1 ? b : c);
  ushort_t* dst = out + (size_t)blockIdx.y * n_each;
  int i = (blockIdx.x * blockDim.x + threadIdx.x) * 4;
  int stride = gridDim.x * blockDim.x * 4;
  for (; i < n_each; i += stride) {
    float4 v = *(const float4*)(src + i);
    ushort4 o;
    o.x = f2b(v.x); o.y = f2b(v.y); o.z = f2b(v.z); o.w = f2b(v.w);
    *(ushort4*)(dst + i) = o;
  }
}

__global__ __launch_bounds__(256) void concat3_f32(const float* __restrict__ a,
                                                   const float* __restrict__ b,
                                                   const float* __restrict__ c,
                                                   float* __restrict__ out, int n) {
  int i = blockIdx.x * blockDim.x + threadIdx.x;
  if (i < n) { out[i] = a[i]; out[n + i] = b[i]; out[2 * n + i] = c[i]; }
}

// ============ 256x256 4-phase K-loop machinery (m201 template port) ============
// 512 thr = 8 waves (2M x 4N); per-wave output: rows {mh*128 + wr*64 .. +63},
// cols {nh*128 + wc*32 + nf*16}.  LDS 128 KiB = [2 buf][4 slots][128x64] bf16,
// slots {0:A-rows0-127, 1:A-rows128-255, 2:B-rows0-127, 3:B-rows128-255},
// XOR swizzle byte_col ^= (row&7)<<4 (write pre-swizzled at source).
// Per K-tile: 4 phases, quadrants (mh,nh) = (0,0)(0,1)(1,1)(1,0); B(nh0) frags
// held in regs across the whole tile so each LDS slot dies in ONE phase:
//   deaths: ph1 -> A0,B0  ph2 -> B1  ph3 -> A1
// staging per phase: ph1: A1(t+1)->nxt  ph2: A0(t+2)->cur  ph3: B0(t+2)->cur
//                    ph4: B1(t+2)->cur, then vmcnt(6): 3 half-tiles in flight.
__device__ inline void stage_half(const ushort_t* __restrict__ G, int ldg,
                                  ushort_t* slot, int w, int lane, int koff) {
  int r = w * 16 + (lane >> 3);
  int scol = ((lane & 7) ^ (lane >> 3)) << 3;  // pre-swizzled source col (elems)
  const ushort_t* src = G + (size_t)r * ldg + koff + scol;
  gload_lds16(src, slot + w * 16 * 64);
  gload_lds16(src + (size_t)8 * ldg, slot + (w * 16 + 8) * 64);
}

#define SBAR0() __builtin_amdgcn_sched_barrier(0)
#define PH_BAR() do { SBAR0(); __builtin_amdgcn_s_barrier(); SBAR0(); } while (0)
#define LGKM0() do { asm volatile("s_waitcnt lgkmcnt(0)" ::: "memory"); SBAR0(); } while (0)

#define LDA_SUB(mh)                                                              \
  _Pragma("unroll") for (int mf = 0; mf < 4; ++mf)                               \
  _Pragma("unroll") for (int ks = 0; ks < 2; ++ks) {                             \
    int r_ = (mh) * 128 + wr * 64 + mf * 16 + fr;                                \
    a[mf][ks] = *(const bf16x8*)(LA + r_ * 128 + ((ks * 64 + g16) ^ ((r_ & 7) << 4))); \
  }

#define LDB_SUB(dst, nh)                                                         \
  _Pragma("unroll") for (int nf = 0; nf < 2; ++nf)                               \
  _Pragma("unroll") for (int ks = 0; ks < 2; ++ks) {                             \
    int r_ = (nh) * 128 + wc * 32 + nf * 16 + fr;                                \
    dst[nf][ks] = *(const bf16x8*)(LB + r_ * 128 + ((ks * 64 + g16) ^ ((r_ & 7) << 4))); \
  }

#define MFMA_Q(mh, nh, bq)                                                       \
  __builtin_amdgcn_s_setprio(1);                                                 \
  _Pragma("unroll") for (int mf = 0; mf < 4; ++mf)                               \
  _Pragma("unroll") for (int nf = 0; nf < 2; ++nf)                               \
  _Pragma("unroll") for (int ks = 0; ks < 2; ++ks)                               \
    acc[(mh) * 4 + mf][(nh) * 2 + nf] = __builtin_amdgcn_mfma_f32_16x16x32_bf16( \
        a[mf][ks], bq[nf][ks], acc[(mh) * 4 + mf][(nh) * 2 + nf], 0, 0, 0);      \
  __builtin_amdgcn_s_setprio(0);

// K-loop over nt 64-wide tiles; A0g/A1g/B0g/B1g are 128-row half sources.
#define KLOOP_256(ldaK, ldbK)                                                    \
  stage_half(A0g, ldaK, &lds[0][0][0], w, lane, 0);                              \
  stage_half(A1g, ldaK, &lds[0][1][0], w, lane, 0);                              \
  stage_half(B0g, ldbK, &lds[0][2][0], w, lane, 0);                              \
  stage_half(B1g, ldbK, &lds[0][3][0], w, lane, 0);                              \
  if (nt > 1) {                                                                  \
    stage_half(A0g, ldaK, &lds[1][0][0], w, lane, 64);                           \
    stage_half(B0g, ldbK, &lds[1][2][0], w, lane, 64);                           \
    stage_half(B1g, ldbK, &lds[1][3][0], w, lane, 64);                           \
    asm volatile("s_waitcnt vmcnt(6)" ::: "memory");                             \
  } else {                                                                       \
    asm volatile("s_waitcnt vmcnt(0)" ::: "memory");                             \
  }                                                                              \
  PH_BAR();                                                                      \
  for (int t = 0; t < nt; ++t) {                                                 \
    const int cur = t & 1, nxt = cur ^ 1;                                        \
    const char* LA = (const char*)&lds[cur][0][0];                               \
    const char* LB = (const char*)&lds[cur][2][0];                               \
    bf16x8 a[4][2], b0[2][2], b1[2][2];                                          \
    LDA_SUB(0);                                                                  \
    LDB_SUB(b0, 0);                                                              \
    if (t + 1 < nt) stage_half(A1g, ldaK, &lds[nxt][1][0], w, lane, (t + 1) * 64); \
    asm volatile("s_waitcnt lgkmcnt(8)" ::: "memory");                           \
    PH_BAR();                                                                    \
    LGKM0();                                                                     \
    MFMA_Q(0, 0, b0);                                                            \
    PH_BAR();                                                                    \
    LDB_SUB(b1, 1);                                                              \
    if (t + 2 < nt) stage_half(A0g, ldaK, &lds[cur][0][0], w, lane, (t + 2) * 64); \
    PH_BAR();                                                                    \
    LGKM0();                                                                     \
    MFMA_Q(0, 1, b1);                                                            \
    PH_BAR();                                                                    \
    LDA_SUB(1);                                                                  \
    if (t + 2 < nt) stage_half(B0g, ldbK, &lds[cur][2][0], w, lane, (t + 2) * 64); \
    PH_BAR();                                                                    \
    LGKM0();                                                                     \
    MFMA_Q(1, 1, b1);                                                            \
    PH_BAR();                                                                    \
    if (t + 2 < nt) {                                                            \
      stage_half(B1g, ldbK, &lds[cur][3][0], w, lane, (t + 2) * 64);             \
      asm volatile("s_waitcnt vmcnt(6)" ::: "memory");                           \
    } else if (t + 1 < nt) {                                                     \
      asm volatile("s_waitcnt vmcnt(0)" ::: "memory");                           \
    }                                                                            \
    PH_BAR();                                                                    \
    MFMA_Q(1, 0, b0);                                                            \
    PH_BAR();                                                                    \
  }

// ---------------- fused QKV projection: C = A @ B^T + bias, bf16 out ----------------
__global__ __launch_bounds__(512, 1) void gemm256_bias(
    const ushort_t* __restrict__ A, const ushort_t* __restrict__ B,
    ushort_t* __restrict__ C, const float* __restrict__ bias,
    int M, int N, int K) {
  __shared__ __align__(16) ushort_t lds[2][4][128 * 64];  // 128 KiB

  // bijective XCD swizzle (grid % 8 == 0)
  int nbx = N >> 8;
  int lin = blockIdx.x;
  int cpx = gridDim.x >> 3;
  int sw = (lin & 7) * cpx + (lin >> 3);
  int by = sw / nbx, bx = sw - by * nbx;

  int tid = threadIdx.x, lane = tid & 63, w = tid >> 6;
  int wr = w >> 2, wc = w & 3;                  // 2x4 wave grid
  int fr = lane & 15, g16 = (lane >> 4) * 16;   // frag row / byte col group

  const ushort_t* Ab = A + (size_t)by * 256 * K;
  const ushort_t* Bb = B + (size_t)bx * 256 * K;
  const ushort_t* A0g = Ab;
  const ushort_t* A1g = Ab + (size_t)128 * K;
  const ushort_t* B0g = Bb;
  const ushort_t* B1g = Bb + (size_t)128 * K;

  f32x4 acc[8][4];
#pragma unroll
  for (int i = 0; i < 8; i++)
#pragma unroll
    for (int j = 0; j < 4; j++) acc[i][j] = (f32x4)(0.f);

  int nt = K >> 6;
  KLOOP_256(K, K);

  // epilogue: C/D layout col=lane&15, row=(lane>>4)*4+j
  int c2 = lane & 15;
  int rb = (lane >> 4) * 4;
#pragma unroll
  for (int ni = 0; ni < 4; ++ni) {
    int nh = ni >> 1, nf = ni & 1;
    int col = bx * 256 + nh * 128 + wc * 32 + nf * 16 + c2;
    float bv = bias[col];
#pragma unroll
    for (int mi = 0; mi < 8; ++mi) {
      int mh = mi >> 2, mf = mi & 3;
#pragma unroll
      for (int j = 0; j < 4; ++j) {
        int row = by * 256 + mh * 128 + wr * 64 + mf * 16 + rb + j;
        C[(size_t)row * N + col] = f2b(acc[mi][ni][j] + bv);
      }
    }
  }
}

// ---------------- scores: P = exp((Q @ K^T) * scale) causal, + rowsum atomics ----------------
// grid (S/256 cols, S/256 rows, batch); skips bx>by; 1024-deep K (feature dim).
__global__ __launch_bounds__(512, 1) void score256(
    const ushort_t* __restrict__ A, const ushort_t* __restrict__ B,
    ushort_t* __restrict__ P, float* __restrict__ rowsum,
    int M, int K, int lda, int ldb, int ldc,
    long bsA, long bsB, long bsC, float scale) {
  int bx = blockIdx.x, by = blockIdx.y, bz = blockIdx.z;
  if (bx > by) return;  // fully-masked causal block: never touched

  __shared__ __align__(16) ushort_t lds[2][4][128 * 64];  // 128 KiB

  int tid = threadIdx.x, lane = tid & 63, w = tid >> 6;
  int wr = w >> 2, wc = w & 3;
  int fr = lane & 15, g16 = (lane >> 4) * 16;

  const ushort_t* Ab = A + (size_t)bz * bsA + (size_t)by * 256 * lda;
  const ushort_t* Bb = B + (size_t)bz * bsB + (size_t)bx * 256 * ldb;
  const ushort_t* A0g = Ab;
  const ushort_t* A1g = Ab + (size_t)128 * lda;
  const ushort_t* B0g = Bb;
  const ushort_t* B1g = Bb + (size_t)128 * ldb;

  f32x4 acc[8][4];
#pragma unroll
  for (int i = 0; i < 8; i++)
#pragma unroll
    for (int j = 0; j < 4; j++) acc[i][j] = (f32x4)(0.f);

  int nt = K >> 6;
  KLOOP_256(lda, ldb);

  // epilogue: exp + causal mask + per-row sums (atomic)
  ushort_t* Cp = P + (size_t)bz * bsC;
  int c2 = lane & 15;
  int rb = (lane >> 4) * 4;
#pragma unroll
  for (int mi = 0; mi < 8; ++mi) {
    int mh = mi >> 2, mf = mi & 3;
#pragma unroll
    for (int j = 0; j < 4; ++j) {
      int row = by * 256 + mh * 128 + wr * 64 + mf * 16 + rb + j;
      float rsum = 0.f;
#pragma unroll
      for (int ni = 0; ni < 4; ++ni) {
        int nh = ni >> 1, nf = ni & 1;
        int col = bx * 256 + nh * 128 + wc * 32 + nf * 16 + c2;
        float e = 0.f;
        if (bx != by || col <= row) e = __expf(acc[mi][ni][j] * scale);
        rsum += e;
        Cp[(size_t)row * ldc + col] = f2b(e);
      }
#pragma unroll
      for (int o = 1; o < 16; o <<= 1) rsum += __shfl_xor(rsum, o);
      if (c2 == 0) atomicAdd(&rowsum[(size_t)bz * M + row], rsum);
    }
  }
}

#undef LDA_SUB
#undef LDB_SUB
#undef MFMA_Q
#undef PH_BAR
#undef LGKM0
#undef SBAR0
#undef KLOOP_256

// ---------------- 128x128 GEMM  C = A @ B^T  (A:[M][K], B:[N][K], bf16) ----------------
// BK=64, XOR-swizzled LDS; 32 MFMA per barrier; 3 blocks/CU.
// MODE 2: C f32 = acc / rowsum[row], K capped at (by+1)*BM (PV, causal-zero P tail)
template <int MODE>
__global__ __launch_bounds__(256, 3) void gemm_bt(
    const ushort_t* __restrict__ A, const ushort_t* __restrict__ B,
    void* __restrict__ Cv, float* __restrict__ rowsum,
    int M, int N, int K, int lda, int ldb, int ldc,
    long bsA, long bsB, long bsC, float scale) {
  int bx = blockIdx.x, by = blockIdx.y, bz = blockIdx.z;

  const ushort_t* Ab = A + (size_t)bz * bsA + (size_t)by * BM * lda;
  const ushort_t* Bb = B + (size_t)bz * bsB + (size_t)bx * BN * ldb;

  int Keff = K;
  if (MODE == 2) { int cap = (by + 1) * BM; Keff = cap < K ? cap : K; }

  __shared__ __align__(16) ushort_t As[BM * BK];  // 16 KiB
  __shared__ __align__(16) ushort_t Bs[BN * BK];  // 16 KiB

  int tid = threadIdx.x;
  int lane = tid & 63;
  int w = tid >> 6;                 // 4 waves
  int wm = w >> 1, wn = w & 1;

  f32x4 acc[4][4];
#pragma unroll
  for (int i = 0; i < 4; i++)
#pragma unroll
    for (int j = 0; j < 4; j++) acc[i][j] = (f32x4)(0.f);

  // staging: wave w covers rows w*32 .. w*32+31 (4 gload_lds of 8 rows each)
  int srow = lane >> 3;                      // 0..7 within 8-row group
  int scol = ((lane & 7) ^ srow) << 3;       // pre-swizzled source col (elems)
  int fr = lane & 15, g16 = (lane >> 4) * 16;

  int nk = Keff / BK;
  for (int kt = 0; kt < nk; ++kt) {
    const ushort_t* Abase = Ab + (size_t)(w * 32 + srow) * lda + kt * BK + scol;
    const ushort_t* Bbase = Bb + (size_t)(w * 32 + srow) * ldb + kt * BK + scol;
#pragma unroll
    for (int j = 0; j < 4; ++j) {
      gload_lds16(Abase + (size_t)(j * 8) * lda, &As[(w * 32 + j * 8) * BK]);
      gload_lds16(Bbase + (size_t)(j * 8) * ldb, &Bs[(w * 32 + j * 8) * BK]);
    }
    __syncthreads();

    bf16x8 af[4][2], bf[4][2];
#pragma unroll
    for (int i = 0; i < 4; i++)
#pragma unroll
      for (int ks = 0; ks < 2; ++ks) {
        int ra = wm * 64 + i * 16 + fr;
        af[i][ks] = *(const bf16x8*)((const char*)As + ra * 128 +
                                     ((ks * 64 + g16) ^ ((ra & 7) << 4)));
        int rb2 = wn * 64 + i * 16 + fr;
        bf[i][ks] = *(const bf16x8*)((const char*)Bs + rb2 * 128 +
                                     ((ks * 64 + g16) ^ ((rb2 & 7) << 4)));
      }
#pragma unroll
    for (int mi = 0; mi < 4; mi++)
#pragma unroll
      for (int ni = 0; ni < 4; ni++)
#pragma unroll
        for (int ks = 0; ks < 2; ++ks)
          acc[mi][ni] = __builtin_amdgcn_mfma_f32_16x16x32_bf16(
              af[mi][ks], bf[ni][ks], acc[mi][ni], 0, 0, 0);
    __syncthreads();
  }

  int c = lane & 15;
  int rb = (lane >> 4) * 4;
  {
    float* C = (float*)Cv + (size_t)bz * bsC;
#pragma unroll
    for (int mi = 0; mi < 4; mi++)
#pragma unroll
      for (int j = 0; j < 4; j++) {
        int row = by * BM + wm * 64 + mi * 16 + rb + j;
        float inv = 1.0f / rowsum[(size_t)bz * M + row];
#pragma unroll
        for (int ni = 0; ni < 4; ni++) {
          int col = bx * BN + wn * 64 + ni * 16 + c;
          C[(size_t)row * ldc + col] = acc[mi][ni][j] * inv;
        }
      }
  }
}

// ---------------- bf16 transpose, 64x64 tiles (128B coalesced both sides) ----------------
__global__ __launch_bounds__(256) void transpose2d(const ushort_t* __restrict__ in,
                                                   ushort_t* __restrict__ out,
                                                   int rows, int cols, int ld_in,
                                                   long bs_in, long bs_out) {
  __shared__ ushort_t tile[64][66];
  int b = blockIdx.z;
  in += (size_t)b * bs_in;
  out += (size_t)b * bs_out;
  int c0 = blockIdx.x * 64, r0 = blockIdx.y * 64;
  int tx = threadIdx.x & 31, ty = threadIdx.x >> 5;
#pragma unroll
  for (int i = ty; i < 64; i += 8) {
    ushort2 v = *(const ushort2*)&in[(size_t)(r0 + i) * ld_in + c0 + 2 * tx];
    tile[i][2 * tx] = v.x;
    tile[i][2 * tx + 1] = v.y;
  }
  __syncthreads();
#pragma unroll
  for (int i = ty; i < 64; i += 8) {
    ushort2 o;
    o.x = tile[2 * tx][i];
    o.y = tile[2 * tx + 1][i];
    *(ushort2*)&out[(size_t)(c0 + i) * rows + r0 + 2 * tx] = o;
  }
}

extern "C" void kernel_launch(void* const* d_in, const int* in_sizes, int n_in,
                              void* d_out, int out_size, void* d_ws, size_t ws_size,
                              hipStream_t stream) {
  const int Bb = 4, S = 2048, E = 1024, A = 1024;
  const int N3 = 3 * A;             // fused projection width 3072
  const size_t M = (size_t)Bb * S;  // 8192
  const float* emb = (const float*)d_in[0];
  const float* Wq = (const float*)d_in[1];
  const float* bq = (const float*)d_in[2];
  const float* Wk = (const float*)d_in[3];
  const float* bk = (const float*)d_in[4];
  const float* Wv = (const float*)d_in[5];
  const float* bv = (const float*)d_in[6];
  float* out = (float*)d_out;

  char* ws = (char*)d_ws;
  // layout (byte offsets):
  ushort_t* QKV  = (ushort_t*)(ws + 0);           // 48 MiB [8192][3072]: Q|K|V
  ushort_t* Vt   = (ushort_t*)(ws + 50331648);    // 16 MiB [b][A][S]
  ushort_t* P    = (ushort_t*)(ws + 67108864);    // 32 MiB [b][S][S] bf16 (unnormalized exp)
  float* rowsum  = (float*)(ws + 100663296);      // 32 KiB [b*S]
  ushort_t* embB = (ushort_t*)(ws + 100696064);   // 16 MiB
  ushort_t* WB   = (ushort_t*)(ws + 117473280);   // 6 MiB = Wq|Wk|Wv bf16 [3072][1024]
  float*    bqkv = (float*)(ws + 123764736);      // 12 KiB
  if (ws_size < 157286400ull) return;             // refuse to corrupt

  cvt_kernel<<<2048, 256, 0, stream>>>(emb, embB, (int)(M * E));
  cvt3_kernel<<<dim3(256, 3), 256, 0, stream>>>(Wq, Wk, Wv, WB, A * E);
  concat3_f32<<<4, 256, 0, stream>>>(bq, bk, bv, bqkv, A);
  hipMemsetAsync(rowsum, 0, (size_t)M * sizeof(float), stream);

  // fused QKV projection: M=8192, N=3072, K=1024 -> 384 blocks of 512 thr
  gemm256_bias<<<dim3((M / 256) * (N3 / 256)), dim3(512), 0, stream>>>(
      embB, WB, QKV, bqkv, (int)M, N3, E);

  // V (cols 2048..3071 of QKV, ld 3072) -> Vt [A][S] per batch
  transpose2d<<<dim3(A / 64, S / 64, Bb), dim3(256), 0, stream>>>(
      QKV + 2 * A, Vt, S, A, N3, (long)S * N3, (long)A * S);

  // scores -> P = exp(QK^T/sqrt(dk)) bf16 + rowsum atomics (256^2 4-phase)
  score256<<<dim3(S / 256, S / 256, Bb), dim3(512), 0, stream>>>(
      QKV /*Q*/, QKV + A /*K*/, P, rowsum, S, E, N3, N3, S,
      (long)S * N3, (long)S * N3, (long)S * S, 0.03125f);

  // PV: per batch M=2048, N=1024, K=2048 (capped per block-row), divide by rowsum
  gemm_bt<2><<<dim3(A / BN, S / BM, Bb), dim3(256), 0, stream>>>(
      P, Vt, out, rowsum, S, A, S, S, S, A,
      (long)S * S, (long)A * S, (long)S * A, 1.f);
}

// Round 4
// 166.293 us; speedup vs baseline: 1.2163x; 1.0055x over previous
//
#include <hip/hip_runtime.h>
#include <hip/hip_bf16.h>
#include <stdint.h>

#define BM 128
#define BN 128
#define BK 64

typedef __attribute__((ext_vector_type(8))) short bf16x8;
typedef __attribute__((ext_vector_type(4))) float f32x4;
typedef unsigned short ushort_t;

__device__ inline unsigned short f2b(float f) {
  unsigned u = __float_as_uint(f);
  unsigned r = (u + 0x7FFFu + ((u >> 16) & 1u)) >> 16;   // RNE, finite inputs
  return (unsigned short)r;
}

__device__ inline void gload_lds16(const void* g, void* l) {
  __builtin_amdgcn_global_load_lds(
      (const __attribute__((address_space(1))) void*)g,
      (__attribute__((address_space(3))) void*)l, 16, 0, 0);
}

// ---------------- f32 -> bf16 convert, 4 elems/thread ----------------
__global__ __launch_bounds__(256) void cvt_kernel(const float* __restrict__ in,
                                                  ushort_t* __restrict__ out, int n) {
  int i = (blockIdx.x * blockDim.x + threadIdx.x) * 4;
  int stride = gridDim.x * blockDim.x * 4;
  for (; i < n; i += stride) {
    float4 v = *(const float4*)(in + i);
    ushort4 o;
    o.x = f2b(v.x); o.y = f2b(v.y); o.z = f2b(v.z); o.w = f2b(v.w);
    *(ushort4*)(out + i) = o;
  }
}

// convert 3 same-size f32 arrays into one contiguous bf16 buffer
__global__ __launch_bounds__(256) void cvt3_kernel(const float* __restrict__ a,
                                                   const float* __restrict__ b,
                                                   const float* __restrict__ c,
                                                   ushort_t* __restrict__ out, int n_each) {
  const float* src = blockIdx.y == 0 ? a : (blockIdx.y == 1 ? b : c);
  ushort_t* dst = out + (size_t)blockIdx.y * n_each;
  int i = (blockIdx.x * blockDim.x + threadIdx.x) * 4;
  int stride = gridDim.x * blockDim.x * 4;
  for (; i < n_each; i += stride) {
    float4 v = *(const float4*)(src + i);
    ushort4 o;
    o.x = f2b(v.x); o.y = f2b(v.y); o.z = f2b(v.z); o.w = f2b(v.w);
    *(ushort4*)(dst + i) = o;
  }
}

__global__ __launch_bounds__(256) void concat3_f32(const float* __restrict__ a,
                                                   const float* __restrict__ b,
                                                   const float* __restrict__ c,
                                                   float* __restrict__ out, int n) {
  int i = blockIdx.x * blockDim.x + threadIdx.x;
  if (i < n) { out[i] = a[i]; out[n + i] = b[i]; out[2 * n + i] = c[i]; }
}

// stage one [128 rows][64 cols] bf16 half-tile: 512 thr x 2 gload_lds of 16B.
// global source col pre-swizzled so linear LDS dest + swizzled read match.
__device__ inline void stage_half(const ushort_t* __restrict__ G, int ldg,
                                  ushort_t* slot, int w, int lane, int koff) {
  int r = w * 16 + (lane >> 3);
  int scol = ((lane & 7) ^ (lane >> 3)) << 3;  // pre-swizzled source col (elems)
  const ushort_t* src = G + (size_t)r * ldg + koff + scol;
  gload_lds16(src, slot + w * 16 * 64);
  gload_lds16(src + (size_t)8 * ldg, slot + (w * 16 + 8) * 64);
}

#define SBAR0() __builtin_amdgcn_sched_barrier(0)
#define PH_BAR() do { SBAR0(); __builtin_amdgcn_s_barrier(); SBAR0(); } while (0)
#define LGKM0() do { asm volatile("s_waitcnt lgkmcnt(0)" ::: "memory"); SBAR0(); } while (0)

// ============ 128x256 2-phase projection GEMM ============
// C[M][N] bf16 = A[M][K] @ B[N][K]^T + bias[col].  Grid 64x12 = 768 = 3 full
// rounds on 256 CUs (vs 256^2's 384 blocks = 1.5 rounds at 2T wall).
// 512 thr = 8 waves (2M x 4N); per-wave output 64 rows x 64 cols (acc[4][4]).
// LDS 96 KiB = [2 buf][3 slots][128x64] bf16, slots {A0, B rows0-127, B rows128-255};
// XOR swizzle byte_col ^= (row&7)<<4.  Wave wc reads only B-slot 1+(wc>>1).
// Per K-tile 2 phases (nf halves 0,1 / 2,3); a-frags read ph1, held in regs.
// Slot deaths: A0 -> ph1; B0,B1 -> ph2.
// Staging: ph1 stages B0,B1(t+1)->nxt; ph2 stages A0(t+2)->cur;
// vmcnt(2) after ph2 MFMA (waits B(t+1)+older, leaves A0(t+2) in flight).
__global__ __launch_bounds__(512, 1) void gemm128x256_bias(
    const ushort_t* __restrict__ A, const ushort_t* __restrict__ B,
    ushort_t* __restrict__ C, const float* __restrict__ bias,
    int M, int N, int K) {
  __shared__ __align__(16) ushort_t lds[2][3][128 * 64];  // 96 KiB

  // bijective XCD swizzle (grid % 8 == 0)
  int nbx = N >> 8;                 // 256-col tiles
  int lin = blockIdx.x;
  int cpx = gridDim.x >> 3;
  int sw = (lin & 7) * cpx + (lin >> 3);
  int by = sw / nbx, bx = sw - by * nbx;

  int tid = threadIdx.x, lane = tid & 63, w = tid >> 6;
  int wr = (w >> 2) & 1, wc = w & 3;            // 2x4 wave grid
  int fr = lane & 15, g16 = (lane >> 4) * 16;   // frag row / byte col group

  const ushort_t* A0g = A + (size_t)by * 128 * K;
  const ushort_t* B0g = B + (size_t)bx * 256 * K;
  const ushort_t* B1g = B0g + (size_t)128 * K;

  f32x4 acc[4][4];
#pragma unroll
  for (int i = 0; i < 4; i++)
#pragma unroll
    for (int j = 0; j < 4; j++) acc[i][j] = (f32x4)(0.f);

  int nt = K >> 6;

  // ---- prologue: tile0 (A0,B0,B1) + A0(1) ----
  stage_half(A0g, K, &lds[0][0][0], w, lane, 0);
  stage_half(B0g, K, &lds[0][1][0], w, lane, 0);
  stage_half(B1g, K, &lds[0][2][0], w, lane, 0);
  if (nt > 1) {
    stage_half(A0g, K, &lds[1][0][0], w, lane, 64);
    asm volatile("s_waitcnt vmcnt(2)" ::: "memory");  // tile0's 6 loads landed
  } else {
    asm volatile("s_waitcnt vmcnt(0)" ::: "memory");
  }
  PH_BAR();

  const int bslot = 1 + (wc >> 1);
  const int brow0 = (wc & 1) * 64;

  for (int t = 0; t < nt; ++t) {
    const int cur = t & 1, nxt = cur ^ 1;
    const char* LA = (const char*)&lds[cur][0][0];
    const char* LB = (const char*)&lds[cur][bslot][0];
    bf16x8 a[4][2], b[2][2];

    // -- phase 1: nf 0,1; 12 ds_reads; stage B0,B1(t+1)->nxt --
#pragma unroll
    for (int mf = 0; mf < 4; ++mf)
#pragma unroll
      for (int ks = 0; ks < 2; ++ks) {
        int r_ = wr * 64 + mf * 16 + fr;
        a[mf][ks] = *(const bf16x8*)(LA + r_ * 128 + ((ks * 64 + g16) ^ ((r_ & 7) << 4)));
      }
#pragma unroll
    for (int nfo = 0; nfo < 2; ++nfo)
#pragma unroll
      for (int ks = 0; ks < 2; ++ks) {
        int r_ = brow0 + nfo * 16 + fr;
        b[nfo][ks] = *(const bf16x8*)(LB + r_ * 128 + ((ks * 64 + g16) ^ ((r_ & 7) << 4)));
      }
    if (t + 1 < nt) {
      stage_half(B0g, K, &lds[nxt][1][0], w, lane, (t + 1) * 64);
      stage_half(B1g, K, &lds[nxt][2][0], w, lane, (t + 1) * 64);
    }
    asm volatile("s_waitcnt lgkmcnt(8)" ::: "memory");
    PH_BAR();
    LGKM0();
    __builtin_amdgcn_s_setprio(1);
#pragma unroll
    for (int mf = 0; mf < 4; ++mf)
#pragma unroll
      for (int nfo = 0; nfo < 2; ++nfo)
#pragma unroll
        for (int ks = 0; ks < 2; ++ks)
          acc[mf][nfo] = __builtin_amdgcn_mfma_f32_16x16x32_bf16(
              a[mf][ks], b[nfo][ks], acc[mf][nfo], 0, 0, 0);
    __builtin_amdgcn_s_setprio(0);
    PH_BAR();

    // -- phase 2: nf 2,3; 4 ds_reads; stage A0(t+2)->cur (slot died ph1) --
#pragma unroll
    for (int nfo = 0; nfo < 2; ++nfo)
#pragma unroll
      for (int ks = 0; ks < 2; ++ks) {
        int r_ = brow0 + (2 + nfo) * 16 + fr;
        b[nfo][ks] = *(const bf16x8*)(LB + r_ * 128 + ((ks * 64 + g16) ^ ((r_ & 7) << 4)));
      }
    if (t + 2 < nt) stage_half(A0g, K, &lds[cur][0][0], w, lane, (t + 2) * 64);
    PH_BAR();
    LGKM0();
    __builtin_amdgcn_s_setprio(1);
#pragma unroll
    for (int mf = 0; mf < 4; ++mf)
#pragma unroll
      for (int nfo = 0; nfo < 2; ++nfo)
#pragma unroll
        for (int ks = 0; ks < 2; ++ks)
          acc[mf][2 + nfo] = __builtin_amdgcn_mfma_f32_16x16x32_bf16(
              a[mf][ks], b[nfo][ks], acc[mf][2 + nfo], 0, 0, 0);
    __builtin_amdgcn_s_setprio(0);
    if (t + 2 < nt) {
      asm volatile("s_waitcnt vmcnt(2)" ::: "memory");  // B(t+1)+A0(t+1) landed
    } else if (t + 1 < nt) {
      asm volatile("s_waitcnt vmcnt(0)" ::: "memory");  // drain before last tile
    }
    PH_BAR();
  }

  // epilogue: C/D layout col=lane&15, row=(lane>>4)*4+j
  int c2 = lane & 15;
  int rb = (lane >> 4) * 4;
#pragma unroll
  for (int nf = 0; nf < 4; ++nf) {
    int col = bx * 256 + wc * 64 + nf * 16 + c2;
    float bv = bias[col];
#pragma unroll
    for (int mf = 0; mf < 4; ++mf)
#pragma unroll
      for (int j = 0; j < 4; ++j) {
        int row = by * 128 + wr * 64 + mf * 16 + rb + j;
        C[(size_t)row * N + col] = f2b(acc[mf][nf][j] + bv);
      }
  }
}

// ============ 256x256 4-phase K-loop machinery (m201 template port) ============
#define LDA_SUB(mh)                                                              \
  _Pragma("unroll") for (int mf = 0; mf < 4; ++mf)                               \
  _Pragma("unroll") for (int ks = 0; ks < 2; ++ks) {                             \
    int r_ = (mh) * 128 + wr * 64 + mf * 16 + fr;                                \
    a[mf][ks] = *(const bf16x8*)(LA + r_ * 128 + ((ks * 64 + g16) ^ ((r_ & 7) << 4))); \
  }

#define LDB_SUB(dst, nh)                                                         \
  _Pragma("unroll") for (int nf = 0; nf < 2; ++nf)                               \
  _Pragma("unroll") for (int ks = 0; ks < 2; ++ks) {                             \
    int r_ = (nh) * 128 + wc * 32 + nf * 16 + fr;                                \
    dst[nf][ks] = *(const bf16x8*)(LB + r_ * 128 + ((ks * 64 + g16) ^ ((r_ & 7) << 4))); \
  }

#define MFMA_Q(mh, nh, bq)                                                       \
  __builtin_amdgcn_s_setprio(1);                                                 \
  _Pragma("unroll") for (int mf = 0; mf < 4; ++mf)                               \
  _Pragma("unroll") for (int nf = 0; nf < 2; ++nf)                               \
  _Pragma("unroll") for (int ks = 0; ks < 2; ++ks)                               \
    acc[(mh) * 4 + mf][(nh) * 2 + nf] = __builtin_amdgcn_mfma_f32_16x16x32_bf16( \
        a[mf][ks], bq[nf][ks], acc[(mh) * 4 + mf][(nh) * 2 + nf], 0, 0, 0);      \
  __builtin_amdgcn_s_setprio(0);

#define KLOOP_256(ldaK, ldbK)                                                    \
  stage_half(A0g, ldaK, &lds[0][0][0], w, lane, 0);                              \
  stage_half(A1g, ldaK, &lds[0][1][0], w, lane, 0);                              \
  stage_half(B0g, ldbK, &lds[0][2][0], w, lane, 0);                              \
  stage_half(B1g, ldbK, &lds[0][3][0], w, lane, 0);                              \
  if (nt > 1) {                                                                  \
    stage_half(A0g, ldaK, &lds[1][0][0], w, lane, 64);                           \
    stage_half(B0g, ldbK, &lds[1][2][0], w, lane, 64);                           \
    stage_half(B1g, ldbK, &lds[1][3][0], w, lane, 64);                           \
    asm volatile("s_waitcnt vmcnt(6)" ::: "memory");                             \
  } else {                                                                       \
    asm volatile("s_waitcnt vmcnt(0)" ::: "memory");                             \
  }                                                                              \
  PH_BAR();                                                                      \
  for (int t = 0; t < nt; ++t) {                                                 \
    const int cur = t & 1, nxt = cur ^ 1;                                        \
    const char* LA = (const char*)&lds[cur][0][0];                               \
    const char* LB = (const char*)&lds[cur][2][0];                               \
    bf16x8 a[4][2], b0[2][2], b1[2][2];                                          \
    LDA_SUB(0);                                                                  \
    LDB_SUB(b0, 0);                                                              \
    if (t + 1 < nt) stage_half(A1g, ldaK, &lds[nxt][1][0], w, lane, (t + 1) * 64); \
    asm volatile("s_waitcnt lgkmcnt(8)" ::: "memory");                           \
    PH_BAR();                                                                    \
    LGKM0();                                                                     \
    MFMA_Q(0, 0, b0);                                                            \
    PH_BAR();                                                                    \
    LDB_SUB(b1, 1);                                                              \
    if (t + 2 < nt) stage_half(A0g, ldaK, &lds[cur][0][0], w, lane, (t + 2) * 64); \
    PH_BAR();                                                                    \
    LGKM0();                                                                     \
    MFMA_Q(0, 1, b1);                                                            \
    PH_BAR();                                                                    \
    LDA_SUB(1);                                                                  \
    if (t + 2 < nt) stage_half(B0g, ldbK, &lds[cur][2][0], w, lane, (t + 2) * 64); \
    PH_BAR();                                                                    \
    LGKM0();                                                                     \
    MFMA_Q(1, 1, b1);                                                            \
    PH_BAR();                                                                    \
    if (t + 2 < nt) {                                                            \
      stage_half(B1g, ldbK, &lds[cur][3][0], w, lane, (t + 2) * 64);             \
      asm volatile("s_waitcnt vmcnt(6)" ::: "memory");                           \
    } else if (t + 1 < nt) {                                                     \
      asm volatile("s_waitcnt vmcnt(0)" ::: "memory");                           \
    }                                                                            \
    PH_BAR();                                                                    \
    MFMA_Q(1, 0, b0);                                                            \
    PH_BAR();                                                                    \
  }

// ---------------- scores: P = exp((Q @ K^T) * scale) causal, + rowsum atomics ----------------
// grid (S/256 cols, S/256 rows, batch); skips bx>by; 1024-deep K (feature dim).
__global__ __launch_bounds__(512, 1) void score256(
    const ushort_t* __restrict__ A, const ushort_t* __restrict__ B,
    ushort_t* __restrict__ P, float* __restrict__ rowsum,
    int M, int K, int lda, int ldb, int ldc,
    long bsA, long bsB, long bsC, float scale) {
  int bx = blockIdx.x, by = blockIdx.y, bz = blockIdx.z;
  if (bx > by) return;  // fully-masked causal block: never touched

  __shared__ __align__(16) ushort_t lds[2][4][128 * 64];  // 128 KiB

  int tid = threadIdx.x, lane = tid & 63, w = tid >> 6;
  int wr = w >> 2, wc = w & 3;
  int fr = lane & 15, g16 = (lane >> 4) * 16;

  const ushort_t* Ab = A + (size_t)bz * bsA + (size_t)by * 256 * lda;
  const ushort_t* Bb = B + (size_t)bz * bsB + (size_t)bx * 256 * ldb;
  const ushort_t* A0g = Ab;
  const ushort_t* A1g = Ab + (size_t)128 * lda;
  const ushort_t* B0g = Bb;
  const ushort_t* B1g = Bb + (size_t)128 * ldb;

  f32x4 acc[8][4];
#pragma unroll
  for (int i = 0; i < 8; i++)
#pragma unroll
    for (int j = 0; j < 4; j++) acc[i][j] = (f32x4)(0.f);

  int nt = K >> 6;
  KLOOP_256(lda, ldb);

  // epilogue: exp + causal mask + per-row sums (atomic)
  ushort_t* Cp = P + (size_t)bz * bsC;
  int c2 = lane & 15;
  int rb = (lane >> 4) * 4;
#pragma unroll
  for (int mi = 0; mi < 8; ++mi) {
    int mh = mi >> 2, mf = mi & 3;
#pragma unroll
    for (int j = 0; j < 4; ++j) {
      int row = by * 256 + mh * 128 + wr * 64 + mf * 16 + rb + j;
      float rsum = 0.f;
#pragma unroll
      for (int ni = 0; ni < 4; ++ni) {
        int nh = ni >> 1, nf = ni & 1;
        int col = bx * 256 + nh * 128 + wc * 32 + nf * 16 + c2;
        float e = 0.f;
        if (bx != by || col <= row) e = __expf(acc[mi][ni][j] * scale);
        rsum += e;
        Cp[(size_t)row * ldc + col] = f2b(e);
      }
#pragma unroll
      for (int o = 1; o < 16; o <<= 1) rsum += __shfl_xor(rsum, o);
      if (c2 == 0) atomicAdd(&rowsum[(size_t)bz * M + row], rsum);
    }
  }
}

#undef LDA_SUB
#undef LDB_SUB
#undef MFMA_Q
#undef PH_BAR
#undef LGKM0
#undef SBAR0
#undef KLOOP_256

// ---------------- 128x128 GEMM  C = A @ B^T  (A:[M][K], B:[N][K], bf16) ----------------
// BK=64, XOR-swizzled LDS; 32 MFMA per barrier; 3 blocks/CU.
// MODE 2: C f32 = acc / rowsum[row], K capped at (by+1)*BM (PV, causal-zero P tail)
template <int MODE>
__global__ __launch_bounds__(256, 3) void gemm_bt(
    const ushort_t* __restrict__ A, const ushort_t* __restrict__ B,
    void* __restrict__ Cv, float* __restrict__ rowsum,
    int M, int N, int K, int lda, int ldb, int ldc,
    long bsA, long bsB, long bsC, float scale) {
  int bx = blockIdx.x, by = blockIdx.y, bz = blockIdx.z;

  const ushort_t* Ab = A + (size_t)bz * bsA + (size_t)by * BM * lda;
  const ushort_t* Bb = B + (size_t)bz * bsB + (size_t)bx * BN * ldb;

  int Keff = K;
  if (MODE == 2) { int cap = (by + 1) * BM; Keff = cap < K ? cap : K; }

  __shared__ __align__(16) ushort_t As[BM * BK];  // 16 KiB
  __shared__ __align__(16) ushort_t Bs[BN * BK];  // 16 KiB

  int tid = threadIdx.x;
  int lane = tid & 63;
  int w = tid >> 6;                 // 4 waves
  int wm = w >> 1, wn = w & 1;

  f32x4 acc[4][4];
#pragma unroll
  for (int i = 0; i < 4; i++)
#pragma unroll
    for (int j = 0; j < 4; j++) acc[i][j] = (f32x4)(0.f);

  // staging: wave w covers rows w*32 .. w*32+31 (4 gload_lds of 8 rows each)
  int srow = lane >> 3;                      // 0..7 within 8-row group
  int scol = ((lane & 7) ^ srow) << 3;       // pre-swizzled source col (elems)
  int fr = lane & 15, g16 = (lane >> 4) * 16;

  int nk = Keff / BK;
  for (int kt = 0; kt < nk; ++kt) {
    const ushort_t* Abase = Ab + (size_t)(w * 32 + srow) * lda + kt * BK + scol;
    const ushort_t* Bbase = Bb + (size_t)(w * 32 + srow) * ldb + kt * BK + scol;
#pragma unroll
    for (int j = 0; j < 4; ++j) {
      gload_lds16(Abase + (size_t)(j * 8) * lda, &As[(w * 32 + j * 8) * BK]);
      gload_lds16(Bbase + (size_t)(j * 8) * ldb, &Bs[(w * 32 + j * 8) * BK]);
    }
    __syncthreads();

    bf16x8 af[4][2], bf[4][2];
#pragma unroll
    for (int i = 0; i < 4; i++)
#pragma unroll
      for (int ks = 0; ks < 2; ++ks) {
        int ra = wm * 64 + i * 16 + fr;
        af[i][ks] = *(const bf16x8*)((const char*)As + ra * 128 +
                                     ((ks * 64 + g16) ^ ((ra & 7) << 4)));
        int rb2 = wn * 64 + i * 16 + fr;
        bf[i][ks] = *(const bf16x8*)((const char*)Bs + rb2 * 128 +
                                     ((ks * 64 + g16) ^ ((rb2 & 7) << 4)));
      }
#pragma unroll
    for (int mi = 0; mi < 4; mi++)
#pragma unroll
      for (int ni = 0; ni < 4; ni++)
#pragma unroll
        for (int ks = 0; ks < 2; ++ks)
          acc[mi][ni] = __builtin_amdgcn_mfma_f32_16x16x32_bf16(
              af[mi][ks], bf[ni][ks], acc[mi][ni], 0, 0, 0);
    __syncthreads();
  }

  int c = lane & 15;
  int rb = (lane >> 4) * 4;
  {
    float* C = (float*)Cv + (size_t)bz * bsC;
#pragma unroll
    for (int mi = 0; mi < 4; mi++)
#pragma unroll
      for (int j = 0; j < 4; j++) {
        int row = by * BM + wm * 64 + mi * 16 + rb + j;
        float inv = 1.0f / rowsum[(size_t)bz * M + row];
#pragma unroll
        for (int ni = 0; ni < 4; ni++) {
          int col = bx * BN + wn * 64 + ni * 16 + c;
          C[(size_t)row * ldc + col] = acc[mi][ni][j] * inv;
        }
      }
  }
}

// ---------------- bf16 transpose, 64x64 tiles (128B coalesced both sides) ----------------
__global__ __launch_bounds__(256) void transpose2d(const ushort_t* __restrict__ in,
                                                   ushort_t* __restrict__ out,
                                                   int rows, int cols, int ld_in,
                                                   long bs_in, long bs_out) {
  __shared__ ushort_t tile[64][66];
  int b = blockIdx.z;
  in += (size_t)b * bs_in;
  out += (size_t)b * bs_out;
  int c0 = blockIdx.x * 64, r0 = blockIdx.y * 64;
  int tx = threadIdx.x & 31, ty = threadIdx.x >> 5;
#pragma unroll
  for (int i = ty; i < 64; i += 8) {
    ushort2 v = *(const ushort2*)&in[(size_t)(r0 + i) * ld_in + c0 + 2 * tx];
    tile[i][2 * tx] = v.x;
    tile[i][2 * tx + 1] = v.y;
  }
  __syncthreads();
#pragma unroll
  for (int i = ty; i < 64; i += 8) {
    ushort2 o;
    o.x = tile[2 * tx][i];
    o.y = tile[2 * tx + 1][i];
    *(ushort2*)&out[(size_t)(c0 + i) * rows + r0 + 2 * tx] = o;
  }
}

extern "C" void kernel_launch(void* const* d_in, const int* in_sizes, int n_in,
                              void* d_out, int out_size, void* d_ws, size_t ws_size,
                              hipStream_t stream) {
  const int Bb = 4, S = 2048, E = 1024, A = 1024;
  const int N3 = 3 * A;             // fused projection width 3072
  const size_t M = (size_t)Bb * S;  // 8192
  const float* emb = (const float*)d_in[0];
  const float* Wq = (const float*)d_in[1];
  const float* bq = (const float*)d_in[2];
  const float* Wk = (const float*)d_in[3];
  const float* bk = (const float*)d_in[4];
  const float* Wv = (const float*)d_in[5];
  const float* bv = (const float*)d_in[6];
  float* out = (float*)d_out;

  char* ws = (char*)d_ws;
  // layout (byte offsets):
  ushort_t* QKV  = (ushort_t*)(ws + 0);           // 48 MiB [8192][3072]: Q|K|V
  ushort_t* Vt   = (ushort_t*)(ws + 50331648);    // 16 MiB [b][A][S]
  ushort_t* P    = (ushort_t*)(ws + 67108864);    // 32 MiB [b][S][S] bf16 (unnormalized exp)
  float* rowsum  = (float*)(ws + 100663296);      // 32 KiB [b*S]
  ushort_t* embB = (ushort_t*)(ws + 100696064);   // 16 MiB
  ushort_t* WB   = (ushort_t*)(ws + 117473280);   // 6 MiB = Wq|Wk|Wv bf16 [3072][1024]
  float*    bqkv = (float*)(ws + 123764736);      // 12 KiB
  if (ws_size < 157286400ull) return;             // refuse to corrupt

  cvt_kernel<<<2048, 256, 0, stream>>>(emb, embB, (int)(M * E));
  cvt3_kernel<<<dim3(256, 3), 256, 0, stream>>>(Wq, Wk, Wv, WB, A * E);
  concat3_f32<<<4, 256, 0, stream>>>(bq, bk, bv, bqkv, A);
  hipMemsetAsync(rowsum, 0, (size_t)M * sizeof(float), stream);

  // fused QKV projection: M=8192, N=3072, K=1024 -> 768 blocks (3 full rounds)
  gemm128x256_bias<<<dim3((M / 128) * (N3 / 256)), dim3(512), 0, stream>>>(
      embB, WB, QKV, bqkv, (int)M, N3, E);

  // V (cols 2048..3071 of QKV, ld 3072) -> Vt [A][S] per batch
  transpose2d<<<dim3(A / 64, S / 64, Bb), dim3(256), 0, stream>>>(
      QKV + 2 * A, Vt, S, A, N3, (long)S * N3, (long)A * S);

  // scores -> P = exp(QK^T/sqrt(dk)) bf16 + rowsum atomics (256^2 4-phase)
  score256<<<dim3(S / 256, S / 256, Bb), dim3(512), 0, stream>>>(
      QKV /*Q*/, QKV + A /*K*/, P, rowsum, S, E, N3, N3, S,
      (long)S * N3, (long)S * N3, (long)S * S, 0.03125f);

  // PV: per batch M=2048, N=1024, K=2048 (capped per block-row), divide by rowsum
  gemm_bt<2><<<dim3(A / BN, S / BM, Bb), dim3(256), 0, stream>>>(
      P, Vt, out, rowsum, S, A, S, S, S, A,
      (long)S * S, (long)A * S, (long)S * A, 1.f);
}

// Round 5
// 162.680 us; speedup vs baseline: 1.2433x; 1.0222x over previous
//
#include <hip/hip_runtime.h>
#include <hip/hip_bf16.h>
#include <stdint.h>

#define BM 128
#define BN 128
#define BK 64

typedef __attribute__((ext_vector_type(8))) short bf16x8;
typedef __attribute__((ext_vector_type(4))) float f32x4;
typedef unsigned short ushort_t;

__device__ inline unsigned short f2b(float f) {
  unsigned u = __float_as_uint(f);
  unsigned r = (u + 0x7FFFu + ((u >> 16) & 1u)) >> 16;   // RNE, finite inputs
  return (unsigned short)r;
}

__device__ inline void gload_lds16(const void* g, void* l) {
  __builtin_amdgcn_global_load_lds(
      (const __attribute__((address_space(1))) void*)g,
      (__attribute__((address_space(3))) void*)l, 16, 0, 0);
}

// ---------------- f32 -> bf16 convert, 4 elems/thread ----------------
__global__ __launch_bounds__(256) void cvt_kernel(const float* __restrict__ in,
                                                  ushort_t* __restrict__ out, int n) {
  int i = (blockIdx.x * blockDim.x + threadIdx.x) * 4;
  int stride = gridDim.x * blockDim.x * 4;
  for (; i < n; i += stride) {
    float4 v = *(const float4*)(in + i);
    ushort4 o;
    o.x = f2b(v.x); o.y = f2b(v.y); o.z = f2b(v.z); o.w = f2b(v.w);
    *(ushort4*)(out + i) = o;
  }
}

// convert 3 same-size f32 arrays into one contiguous bf16 buffer
__global__ __launch_bounds__(256) void cvt3_kernel(const float* __restrict__ a,
                                                   const float* __restrict__ b,
                                                   const float* __restrict__ c,
                                                   ushort_t* __restrict__ out, int n_each) {
  const float* src = blockIdx.y == 0 ? a : (blockIdx.y == 1 ? b : c);
  ushort_t* dst = out + (size_t)blockIdx.y * n_each;
  int i = (blockIdx.x * blockDim.x + threadIdx.x) * 4;
  int stride = gridDim.x * blockDim.x * 4;
  for (; i < n_each; i += stride) {
    float4 v = *(const float4*)(src + i);
    ushort4 o;
    o.x = f2b(v.x); o.y = f2b(v.y); o.z = f2b(v.z); o.w = f2b(v.w);
    *(ushort4*)(dst + i) = o;
  }
}

__global__ __launch_bounds__(256) void concat3_f32(const float* __restrict__ a,
                                                   const float* __restrict__ b,
                                                   const float* __restrict__ c,
                                                   float* __restrict__ out, int n) {
  int i = blockIdx.x * blockDim.x + threadIdx.x;
  if (i < n) { out[i] = a[i]; out[n + i] = b[i]; out[2 * n + i] = c[i]; }
}

// stage one [128 rows][64 cols] bf16 half-tile: 512 thr x 2 gload_lds of 16B.
// global source col pre-swizzled so linear LDS dest + swizzled read match.
__device__ inline void stage_half(const ushort_t* __restrict__ G, int ldg,
                                  ushort_t* slot, int w, int lane, int koff) {
  int r = w * 16 + (lane >> 3);
  int scol = ((lane & 7) ^ (lane >> 3)) << 3;  // pre-swizzled source col (elems)
  const ushort_t* src = G + (size_t)r * ldg + koff + scol;
  gload_lds16(src, slot + w * 16 * 64);
  gload_lds16(src + (size_t)8 * ldg, slot + (w * 16 + 8) * 64);
}

// stage one [64 rows][64 cols] bf16 tile: 512 thr x 1 gload_lds of 16B.
__device__ inline void stage_64(const ushort_t* __restrict__ G, int ldg,
                                ushort_t* slot, int w, int lane, int koff) {
  int r = w * 8 + (lane >> 3);
  int scol = ((lane & 7) ^ (lane >> 3)) << 3;  // (r&7)==(lane>>3): same swizzle
  const ushort_t* src = G + (size_t)r * ldg + koff + scol;
  gload_lds16(src, slot + w * 8 * 64);
}

#define SBAR0() __builtin_amdgcn_sched_barrier(0)
#define PH_BAR() do { SBAR0(); __builtin_amdgcn_s_barrier(); SBAR0(); } while (0)
#define LGKM0() do { asm volatile("s_waitcnt lgkmcnt(0)" ::: "memory"); SBAR0(); } while (0)

// ============ 256x192 4-phase projection GEMM ============
// C[M][N] bf16 = A[M][K] @ B[N][K]^T + bias[col].  Grid 32x16 = 512 = exactly
// 2 full rounds of 256 CUs (tail-free) AND 4-phase interleave (the 943-TF-class
// structure; R4 showed 2-phase caps at ~750 TF per-active).
// 512 thr = 8 waves (2M x 4N); per-wave output 128 rows x 48 cols (acc[8][3]).
// LDS 112 KiB = [2 buf][A 256x64 | B 192x64] bf16, XOR swizzle byte^=(row&7)<<4.
// Phases = M-quarters mq=0..3 (12 MFMA each); B frags read ph1, held in regs.
// Slot deaths: B -> ph1; A -> ph4.
// Staging: ph1: A(t+1)->nxt (4x stage_64; slot died ph4(t-1));
//          ph3: B(t+2)->cur (3x stage_64; slot died ph1(t)).
// vmcnt(3) once per tile (end ph4): outstanding = B(t+1)3 + A(t+1)4 + B(t+2)3
// = 10, drains oldest 7 = exactly what tile t+1 reads; B(t+2) stays in flight.
__global__ __launch_bounds__(512, 1) void gemm256x192_bias(
    const ushort_t* __restrict__ A, const ushort_t* __restrict__ B,
    ushort_t* __restrict__ C, const float* __restrict__ bias,
    int M, int N, int K) {
  __shared__ __align__(16) ushort_t lds[2][(256 + 192) * 64];  // 112 KiB
  const int BOFF = 256 * 64;  // B-slot offset (elems)

  // bijective XCD swizzle (grid % 8 == 0)
  int nbx = N / 192;
  int lin = blockIdx.x;
  int cpx = gridDim.x >> 3;
  int sw = (lin & 7) * cpx + (lin >> 3);
  int by = sw / nbx, bx = sw - by * nbx;

  int tid = threadIdx.x, lane = tid & 63, w = tid >> 6;
  int wr = w >> 2, wc = w & 3;                  // 2x4 wave grid
  int fr = lane & 15, g16 = (lane >> 4) * 16;   // frag row / byte col group

  const ushort_t* Ag = A + (size_t)by * 256 * K;
  const ushort_t* Bg = B + (size_t)bx * 192 * K;

  f32x4 acc[8][3];
#pragma unroll
  for (int i = 0; i < 8; i++)
#pragma unroll
    for (int j = 0; j < 3; j++) acc[i][j] = (f32x4)(0.f);

  int nt = K >> 6;

  // ---- prologue: A(0),B(0) -> buf0; B(1) -> buf1 ----
#pragma unroll
  for (int q = 0; q < 4; ++q)
    stage_64(Ag + (size_t)q * 64 * K, K, &lds[0][q * 4096], w, lane, 0);
#pragma unroll
  for (int q = 0; q < 3; ++q)
    stage_64(Bg + (size_t)q * 64 * K, K, &lds[0][BOFF + q * 4096], w, lane, 0);
  if (nt > 1) {
#pragma unroll
    for (int q = 0; q < 3; ++q)
      stage_64(Bg + (size_t)q * 64 * K, K, &lds[1][BOFF + q * 4096], w, lane, 64);
    asm volatile("s_waitcnt vmcnt(3)" ::: "memory");  // tile0's 7 loads landed
  } else {
    asm volatile("s_waitcnt vmcnt(0)" ::: "memory");
  }
  PH_BAR();

  for (int t = 0; t < nt; ++t) {
    const int cur = t & 1, nxt = cur ^ 1;
    const char* LA = (const char*)&lds[cur][0];
    const char* LB = (const char*)&lds[cur][BOFF];
    bf16x8 a[2][2], b[3][2];

    // -- phase 1 (mq=0): 4 A-reads + 6 B-reads; stage A(t+1)->nxt --
#pragma unroll
    for (int mfl = 0; mfl < 2; ++mfl)
#pragma unroll
      for (int ks = 0; ks < 2; ++ks) {
        int r_ = wr * 128 + 0 * 32 + mfl * 16 + fr;
        a[mfl][ks] = *(const bf16x8*)(LA + r_ * 128 + ((ks * 64 + g16) ^ ((r_ & 7) << 4)));
      }
#pragma unroll
    for (int nf = 0; nf < 3; ++nf)
#pragma unroll
      for (int ks = 0; ks < 2; ++ks) {
        int r_ = wc * 48 + nf * 16 + fr;
        b[nf][ks] = *(const bf16x8*)(LB + r_ * 128 + ((ks * 64 + g16) ^ ((r_ & 7) << 4)));
      }
    if (t + 1 < nt) {
#pragma unroll
      for (int q = 0; q < 4; ++q)
        stage_64(Ag + (size_t)q * 64 * K, K, &lds[nxt][q * 4096], w, lane, (t + 1) * 64);
    }
    asm volatile("s_waitcnt lgkmcnt(6)" ::: "memory");
    PH_BAR();
    LGKM0();
    __builtin_amdgcn_s_setprio(1);
#pragma unroll
    for (int mfl = 0; mfl < 2; ++mfl)
#pragma unroll
      for (int nf = 0; nf < 3; ++nf)
#pragma unroll
        for (int ks = 0; ks < 2; ++ks)
          acc[mfl][nf] = __builtin_amdgcn_mfma_f32_16x16x32_bf16(
              a[mfl][ks], b[nf][ks], acc[mfl][nf], 0, 0, 0);
    __builtin_amdgcn_s_setprio(0);
    PH_BAR();

    // -- phases 2..4 (mq=1..3): 4 A-reads each; ph3 stages B(t+2)->cur --
#pragma unroll
    for (int mq = 1; mq < 4; ++mq) {
#pragma unroll
      for (int mfl = 0; mfl < 2; ++mfl)
#pragma unroll
        for (int ks = 0; ks < 2; ++ks) {
          int r_ = wr * 128 + mq * 32 + mfl * 16 + fr;
          a[mfl][ks] = *(const bf16x8*)(LA + r_ * 128 + ((ks * 64 + g16) ^ ((r_ & 7) << 4)));
        }
      if (mq == 2 && t + 2 < nt) {
#pragma unroll
        for (int q = 0; q < 3; ++q)
          stage_64(Bg + (size_t)q * 64 * K, K, &lds[cur][BOFF + q * 4096], w, lane,
                   (t + 2) * 64);
      }
      PH_BAR();
      LGKM0();
      __builtin_amdgcn_s_setprio(1);
#pragma unroll
      for (int mfl = 0; mfl < 2; ++mfl)
#pragma unroll
        for (int nf = 0; nf < 3; ++nf)
#pragma unroll
          for (int ks = 0; ks < 2; ++ks)
            acc[mq * 2 + mfl][nf] = __builtin_amdgcn_mfma_f32_16x16x32_bf16(
                a[mfl][ks], b[nf][ks], acc[mq * 2 + mfl][nf], 0, 0, 0);
      __builtin_amdgcn_s_setprio(0);
      if (mq == 3) {
        if (t + 2 < nt) {
          asm volatile("s_waitcnt vmcnt(3)" ::: "memory");  // tile t+1 landed
        } else if (t + 1 < nt) {
          asm volatile("s_waitcnt vmcnt(0)" ::: "memory");  // drain: last prefetch
        }
      }
      PH_BAR();
    }
  }

  // epilogue: C/D layout col=lane&15, row=(lane>>4)*4+j
  int c2 = lane & 15;
  int rb = (lane >> 4) * 4;
#pragma unroll
  for (int nf = 0; nf < 3; ++nf) {
    int col = bx * 192 + wc * 48 + nf * 16 + c2;
    float bv = bias[col];
#pragma unroll
    for (int mi = 0; mi < 8; ++mi)
#pragma unroll
      for (int j = 0; j < 4; ++j) {
        int row = by * 256 + wr * 128 + mi * 16 + rb + j;
        C[(size_t)row * N + col] = f2b(acc[mi][nf][j] + bv);
      }
  }
}

// ============ 256x256 4-phase K-loop machinery (m201 template port) ============
#define LDA_SUB(mh)                                                              \
  _Pragma("unroll") for (int mf = 0; mf < 4; ++mf)                               \
  _Pragma("unroll") for (int ks = 0; ks < 2; ++ks) {                             \
    int r_ = (mh) * 128 + wr * 64 + mf * 16 + fr;                                \
    a[mf][ks] = *(const bf16x8*)(LA + r_ * 128 + ((ks * 64 + g16) ^ ((r_ & 7) << 4))); \
  }

#define LDB_SUB(dst, nh)                                                         \
  _Pragma("unroll") for (int nf = 0; nf < 2; ++nf)                               \
  _Pragma("unroll") for (int ks = 0; ks < 2; ++ks) {                             \
    int r_ = (nh) * 128 + wc * 32 + nf * 16 + fr;                                \
    dst[nf][ks] = *(const bf16x8*)(LB + r_ * 128 + ((ks * 64 + g16) ^ ((r_ & 7) << 4))); \
  }

#define MFMA_Q(mh, nh, bq)                                                       \
  __builtin_amdgcn_s_setprio(1);                                                 \
  _Pragma("unroll") for (int mf = 0; mf < 4; ++mf)                               \
  _Pragma("unroll") for (int nf = 0; nf < 2; ++nf)                               \
  _Pragma("unroll") for (int ks = 0; ks < 2; ++ks)                               \
    acc[(mh) * 4 + mf][(nh) * 2 + nf] = __builtin_amdgcn_mfma_f32_16x16x32_bf16( \
        a[mf][ks], bq[nf][ks], acc[(mh) * 4 + mf][(nh) * 2 + nf], 0, 0, 0);      \
  __builtin_amdgcn_s_setprio(0);

#define KLOOP_256(ldaK, ldbK)                                                    \
  stage_half(A0g, ldaK, &lds[0][0][0], w, lane, 0);                              \
  stage_half(A1g, ldaK, &lds[0][1][0], w, lane, 0);                              \
  stage_half(B0g, ldbK, &lds[0][2][0], w, lane, 0);                              \
  stage_half(B1g, ldbK, &lds[0][3][0], w, lane, 0);                              \
  if (nt > 1) {                                                                  \
    stage_half(A0g, ldaK, &lds[1][0][0], w, lane, 64);                           \
    stage_half(B0g, ldbK, &lds[1][2][0], w, lane, 64);                           \
    stage_half(B1g, ldbK, &lds[1][3][0], w, lane, 64);                           \
    asm volatile("s_waitcnt vmcnt(6)" ::: "memory");                             \
  } else {                                                                       \
    asm volatile("s_waitcnt vmcnt(0)" ::: "memory");                             \
  }                                                                              \
  PH_BAR();                                                                      \
  for (int t = 0; t < nt; ++t) {                                                 \
    const int cur = t & 1, nxt = cur ^ 1;                                        \
    const char* LA = (const char*)&lds[cur][0][0];                               \
    const char* LB = (const char*)&lds[cur][2][0];                               \
    bf16x8 a[4][2], b0[2][2], b1[2][2];                                          \
    LDA_SUB(0);                                                                  \
    LDB_SUB(b0, 0);                                                              \
    if (t + 1 < nt) stage_half(A1g, ldaK, &lds[nxt][1][0], w, lane, (t + 1) * 64); \
    asm volatile("s_waitcnt lgkmcnt(8)" ::: "memory");                           \
    PH_BAR();                                                                    \
    LGKM0();                                                                     \
    MFMA_Q(0, 0, b0);                                                            \
    PH_BAR();                                                                    \
    LDB_SUB(b1, 1);                                                              \
    if (t + 2 < nt) stage_half(A0g, ldaK, &lds[cur][0][0], w, lane, (t + 2) * 64); \
    PH_BAR();                                                                    \
    LGKM0();                                                                     \
    MFMA_Q(0, 1, b1);                                                            \
    PH_BAR();                                                                    \
    LDA_SUB(1);                                                                  \
    if (t + 2 < nt) stage_half(B0g, ldbK, &lds[cur][2][0], w, lane, (t + 2) * 64); \
    PH_BAR();                                                                    \
    LGKM0();                                                                     \
    MFMA_Q(1, 1, b1);                                                            \
    PH_BAR();                                                                    \
    if (t + 2 < nt) {                                                            \
      stage_half(B1g, ldbK, &lds[cur][3][0], w, lane, (t + 2) * 64);             \
      asm volatile("s_waitcnt vmcnt(6)" ::: "memory");                           \
    } else if (t + 1 < nt) {                                                     \
      asm volatile("s_waitcnt vmcnt(0)" ::: "memory");                           \
    }                                                                            \
    PH_BAR();                                                                    \
    MFMA_Q(1, 0, b0);                                                            \
    PH_BAR();                                                                    \
  }

// ---------------- scores: P = exp((Q @ K^T) * scale) causal, + rowsum atomics ----------------
// grid (S/256 cols, S/256 rows, batch); skips bx>by; 1024-deep K (feature dim).
__global__ __launch_bounds__(512, 1) void score256(
    const ushort_t* __restrict__ A, const ushort_t* __restrict__ B,
    ushort_t* __restrict__ P, float* __restrict__ rowsum,
    int M, int K, int lda, int ldb, int ldc,
    long bsA, long bsB, long bsC, float scale) {
  int bx = blockIdx.x, by = blockIdx.y, bz = blockIdx.z;
  if (bx > by) return;  // fully-masked causal block: never touched

  __shared__ __align__(16) ushort_t lds[2][4][128 * 64];  // 128 KiB

  int tid = threadIdx.x, lane = tid & 63, w = tid >> 6;
  int wr = w >> 2, wc = w & 3;
  int fr = lane & 15, g16 = (lane >> 4) * 16;

  const ushort_t* Ab = A + (size_t)bz * bsA + (size_t)by * 256 * lda;
  const ushort_t* Bb = B + (size_t)bz * bsB + (size_t)bx * 256 * ldb;
  const ushort_t* A0g = Ab;
  const ushort_t* A1g = Ab + (size_t)128 * lda;
  const ushort_t* B0g = Bb;
  const ushort_t* B1g = Bb + (size_t)128 * ldb;

  f32x4 acc[8][4];
#pragma unroll
  for (int i = 0; i < 8; i++)
#pragma unroll
    for (int j = 0; j < 4; j++) acc[i][j] = (f32x4)(0.f);

  int nt = K >> 6;
  KLOOP_256(lda, ldb);

  // epilogue: exp + causal mask + per-row sums (atomic)
  ushort_t* Cp = P + (size_t)bz * bsC;
  int c2 = lane & 15;
  int rb = (lane >> 4) * 4;
#pragma unroll
  for (int mi = 0; mi < 8; ++mi) {
    int mh = mi >> 2, mf = mi & 3;
#pragma unroll
    for (int j = 0; j < 4; ++j) {
      int row = by * 256 + mh * 128 + wr * 64 + mf * 16 + rb + j;
      float rsum = 0.f;
#pragma unroll
      for (int ni = 0; ni < 4; ++ni) {
        int nh = ni >> 1, nf = ni & 1;
        int col = bx * 256 + nh * 128 + wc * 32 + nf * 16 + c2;
        float e = 0.f;
        if (bx != by || col <= row) e = __expf(acc[mi][ni][j] * scale);
        rsum += e;
        Cp[(size_t)row * ldc + col] = f2b(e);
      }
#pragma unroll
      for (int o = 1; o < 16; o <<= 1) rsum += __shfl_xor(rsum, o);
      if (c2 == 0) atomicAdd(&rowsum[(size_t)bz * M + row], rsum);
    }
  }
}

#undef LDA_SUB
#undef LDB_SUB
#undef MFMA_Q
#undef PH_BAR
#undef LGKM0
#undef SBAR0
#undef KLOOP_256

// ---------------- 128x128 GEMM  C = A @ B^T  (A:[M][K], B:[N][K], bf16) ----------------
// BK=64, XOR-swizzled LDS; 32 MFMA per barrier; 3 blocks/CU.
// MODE 2: C f32 = acc / rowsum[row], K capped at (by+1)*BM (PV, causal-zero P tail)
template <int MODE>
__global__ __launch_bounds__(256, 3) void gemm_bt(
    const ushort_t* __restrict__ A, const ushort_t* __restrict__ B,
    void* __restrict__ Cv, float* __restrict__ rowsum,
    int M, int N, int K, int lda, int ldb, int ldc,
    long bsA, long bsB, long bsC, float scale) {
  int bx = blockIdx.x, by = blockIdx.y, bz = blockIdx.z;

  const ushort_t* Ab = A + (size_t)bz * bsA + (size_t)by * BM * lda;
  const ushort_t* Bb = B + (size_t)bz * bsB + (size_t)bx * BN * ldb;

  int Keff = K;
  if (MODE == 2) { int cap = (by + 1) * BM; Keff = cap < K ? cap : K; }

  __shared__ __align__(16) ushort_t As[BM * BK];  // 16 KiB
  __shared__ __align__(16) ushort_t Bs[BN * BK];  // 16 KiB

  int tid = threadIdx.x;
  int lane = tid & 63;
  int w = tid >> 6;                 // 4 waves
  int wm = w >> 1, wn = w & 1;

  f32x4 acc[4][4];
#pragma unroll
  for (int i = 0; i < 4; i++)
#pragma unroll
    for (int j = 0; j < 4; j++) acc[i][j] = (f32x4)(0.f);

  // staging: wave w covers rows w*32 .. w*32+31 (4 gload_lds of 8 rows each)
  int srow = lane >> 3;                      // 0..7 within 8-row group
  int scol = ((lane & 7) ^ srow) << 3;       // pre-swizzled source col (elems)
  int fr = lane & 15, g16 = (lane >> 4) * 16;

  int nk = Keff / BK;
  for (int kt = 0; kt < nk; ++kt) {
    const ushort_t* Abase = Ab + (size_t)(w * 32 + srow) * lda + kt * BK + scol;
    const ushort_t* Bbase = Bb + (size_t)(w * 32 + srow) * ldb + kt * BK + scol;
#pragma unroll
    for (int j = 0; j < 4; ++j) {
      gload_lds16(Abase + (size_t)(j * 8) * lda, &As[(w * 32 + j * 8) * BK]);
      gload_lds16(Bbase + (size_t)(j * 8) * ldb, &Bs[(w * 32 + j * 8) * BK]);
    }
    __syncthreads();

    bf16x8 af[4][2], bf[4][2];
#pragma unroll
    for (int i = 0; i < 4; i++)
#pragma unroll
      for (int ks = 0; ks < 2; ++ks) {
        int ra = wm * 64 + i * 16 + fr;
        af[i][ks] = *(const bf16x8*)((const char*)As + ra * 128 +
                                     ((ks * 64 + g16) ^ ((ra & 7) << 4)));
        int rb2 = wn * 64 + i * 16 + fr;
        bf[i][ks] = *(const bf16x8*)((const char*)Bs + rb2 * 128 +
                                     ((ks * 64 + g16) ^ ((rb2 & 7) << 4)));
      }
#pragma unroll
    for (int mi = 0; mi < 4; mi++)
#pragma unroll
      for (int ni = 0; ni < 4; ni++)
#pragma unroll
        for (int ks = 0; ks < 2; ++ks)
          acc[mi][ni] = __builtin_amdgcn_mfma_f32_16x16x32_bf16(
              af[mi][ks], bf[ni][ks], acc[mi][ni], 0, 0, 0);
    __syncthreads();
  }

  int c = lane & 15;
  int rb = (lane >> 4) * 4;
  {
    float* C = (float*)Cv + (size_t)bz * bsC;
#pragma unroll
    for (int mi = 0; mi < 4; mi++)
#pragma unroll
      for (int j = 0; j < 4; j++) {
        int row = by * BM + wm * 64 + mi * 16 + rb + j;
        float inv = 1.0f / rowsum[(size_t)bz * M + row];
#pragma unroll
        for (int ni = 0; ni < 4; ni++) {
          int col = bx * BN + wn * 64 + ni * 16 + c;
          C[(size_t)row * ldc + col] = acc[mi][ni][j] * inv;
        }
      }
  }
}

// ---------------- bf16 transpose, 64x64 tiles (128B coalesced both sides) ----------------
__global__ __launch_bounds__(256) void transpose2d(const ushort_t* __restrict__ in,
                                                   ushort_t* __restrict__ out,
                                                   int rows, int cols, int ld_in,
                                                   long bs_in, long bs_out) {
  __shared__ ushort_t tile[64][66];
  int b = blockIdx.z;
  in += (size_t)b * bs_in;
  out += (size_t)b * bs_out;
  int c0 = blockIdx.x * 64, r0 = blockIdx.y * 64;
  int tx = threadIdx.x & 31, ty = threadIdx.x >> 5;
#pragma unroll
  for (int i = ty; i < 64; i += 8) {
    ushort2 v = *(const ushort2*)&in[(size_t)(r0 + i) * ld_in + c0 + 2 * tx];
    tile[i][2 * tx] = v.x;
    tile[i][2 * tx + 1] = v.y;
  }
  __syncthreads();
#pragma unroll
  for (int i = ty; i < 64; i += 8) {
    ushort2 o;
    o.x = tile[2 * tx][i];
    o.y = tile[2 * tx + 1][i];
    *(ushort2*)&out[(size_t)(c0 + i) * rows + r0 + 2 * tx] = o;
  }
}

extern "C" void kernel_launch(void* const* d_in, const int* in_sizes, int n_in,
                              void* d_out, int out_size, void* d_ws, size_t ws_size,
                              hipStream_t stream) {
  const int Bb = 4, S = 2048, E = 1024, A = 1024;
  const int N3 = 3 * A;             // fused projection width 3072
  const size_t M = (size_t)Bb * S;  // 8192
  const float* emb = (const float*)d_in[0];
  const float* Wq = (const float*)d_in[1];
  const float* bq = (const float*)d_in[2];
  const float* Wk = (const float*)d_in[3];
  const float* bk = (const float*)d_in[4];
  const float* Wv = (const float*)d_in[5];
  const float* bv = (const float*)d_in[6];
  float* out = (float*)d_out;

  char* ws = (char*)d_ws;
  // layout (byte offsets):
  ushort_t* QKV  = (ushort_t*)(ws + 0);           // 48 MiB [8192][3072]: Q|K|V
  ushort_t* Vt   = (ushort_t*)(ws + 50331648);    // 16 MiB [b][A][S]
  ushort_t* P    = (ushort_t*)(ws + 67108864);    // 32 MiB [b][S][S] bf16 (unnormalized exp)
  float* rowsum  = (float*)(ws + 100663296);      // 32 KiB [b*S]
  ushort_t* embB = (ushort_t*)(ws + 100696064);   // 16 MiB
  ushort_t* WB   = (ushort_t*)(ws + 117473280);   // 6 MiB = Wq|Wk|Wv bf16 [3072][1024]
  float*    bqkv = (float*)(ws + 123764736);      // 12 KiB
  if (ws_size < 157286400ull) return;             // refuse to corrupt

  cvt_kernel<<<2048, 256, 0, stream>>>(emb, embB, (int)(M * E));
  cvt3_kernel<<<dim3(256, 3), 256, 0, stream>>>(Wq, Wk, Wv, WB, A * E);
  concat3_f32<<<4, 256, 0, stream>>>(bq, bk, bv, bqkv, A);
  hipMemsetAsync(rowsum, 0, (size_t)M * sizeof(float), stream);

  // fused QKV projection: M=8192, N=3072, K=1024 -> 32x16 = 512 blocks (2 rounds)
  gemm256x192_bias<<<dim3((M / 256) * (N3 / 192)), dim3(512), 0, stream>>>(
      embB, WB, QKV, bqkv, (int)M, N3, E);

  // V (cols 2048..3071 of QKV, ld 3072) -> Vt [A][S] per batch
  transpose2d<<<dim3(A / 64, S / 64, Bb), dim3(256), 0, stream>>>(
      QKV + 2 * A, Vt, S, A, N3, (long)S * N3, (long)A * S);

  // scores -> P = exp(QK^T/sqrt(dk)) bf16 + rowsum atomics (256^2 4-phase)
  score256<<<dim3(S / 256, S / 256, Bb), dim3(512), 0, stream>>>(
      QKV /*Q*/, QKV + A /*K*/, P, rowsum, S, E, N3, N3, S,
      (long)S * N3, (long)S * N3, (long)S * S, 0.03125f);

  // PV: per batch M=2048, N=1024, K=2048 (capped per block-row), divide by rowsum
  gemm_bt<2><<<dim3(A / BN, S / BM, Bb), dim3(256), 0, stream>>>(
      P, Vt, out, rowsum, S, A, S, S, S, A,
      (long)S * S, (long)A * S, (long)S * A, 1.f);
}